// Round 8
// baseline (549.060 us; speedup 1.0000x reference)
//
#include <hip/hip_runtime.h>
#include <hip/hip_bf16.h>

#define NN 50000
#define EE 850000

typedef unsigned short u16;
using short8 = __attribute__((ext_vector_type(8))) short;
using f32x4  = __attribute__((ext_vector_type(4))) float;

__device__ __forceinline__ float bf2f(u16 u) {
    union { unsigned int i; float f; } v; v.i = ((unsigned int)u) << 16; return v.f;
}
__device__ __forceinline__ u16 f2bf(float f) {
    __hip_bfloat16 h = __float2bfloat16(f);
    return *reinterpret_cast<u16*>(&h);
}

__device__ __forceinline__ float ld1(const void* X, size_t i, bool f32m) {
    return f32m ? ((const float*)X)[i] : bf2f(((const u16*)X)[i]);
}
__device__ __forceinline__ void load4(const void* X, size_t g, bool f32m, float o[4]) {
    if (f32m) {
        float4 v = ((const float4*)X)[g];
        o[0] = v.x; o[1] = v.y; o[2] = v.z; o[3] = v.w;
    } else {
        ushort4 v = ((const ushort4*)X)[g];
        o[0] = bf2f(v.x); o[1] = bf2f(v.y); o[2] = bf2f(v.z); o[3] = bf2f(v.w);
    }
}

// ---- block 0: dtype detect; blocks 1..196: zero deg ----
__global__ void k_detect(const u16* __restrict__ hh, int* __restrict__ flag,
                         int* __restrict__ deg) {
    if (blockIdx.x != 0) {
        int i = (blockIdx.x - 1) * 256 + threadIdx.x;
        if (i < NN) deg[i] = 0;
        return;
    }
    __shared__ int sm[256];
    int t = threadIdx.x;
    int c = 0;
    for (int i = 0; i < 16; ++i) {
        u16 u = hh[t * 16 + i];
        int e = (u >> 7) & 0xFF;
        if (e != 0 && (e < 90 || e > 160)) ++c;
    }
    sm[t] = c;
    __syncthreads();
    for (int s = 128; s > 0; s >>= 1) {
        if (t < s) sm[t] += sm[t + s];
        __syncthreads();
    }
    if (t == 0) *flag = (sm[0] > 200) ? 1 : 0;
}

// ---- fused prep: 0..511 B-transpose, 512..527 attn vecs, rest deg count ----
__global__ void k_prep(const void* __restrict__ W1s, const void* __restrict__ al1,
                       const void* __restrict__ W1d, const void* __restrict__ ar1,
                       const void* __restrict__ W2s, const void* __restrict__ al2,
                       const void* __restrict__ W2d, const void* __restrict__ ar2,
                       const void* __restrict__ Wres2, const int* __restrict__ dst,
                       u16* __restrict__ BT1, u16* __restrict__ BT2,
                       float* __restrict__ wl1, float* __restrict__ wr1,
                       float* __restrict__ wl2, float* __restrict__ wr2,
                       int* __restrict__ deg, const int* __restrict__ mode) {
    int bid = blockIdx.x;
    if (bid >= 528) {
        int e = (bid - 528) * 256 + threadIdx.x;
        if (e < EE) atomicAdd(&deg[dst[e]], 1);
        return;
    }
    bool f32m = (*mode) != 0;
    if (bid < 512) {
        int id = bid * 256 + threadIdx.x;  // 0..131071
        int which = id >> 16;
        int rem = id & 65535;
        int n = rem >> 8, k = rem & 255;
        if (which == 0) {
            BT1[n * 256 + k] = f2bf(ld1(W1s, (size_t)k * 256 + n, f32m));
        } else {
            float v = (n < 128) ? ld1(W2s, (size_t)k * 128 + n, f32m)
                                : ld1(Wres2, (size_t)k * 128 + (n - 128), f32m);
            BT2[n * 256 + k] = f2bf(v);
        }
    } else {
        int id = (bid - 512) * 256 + threadIdx.x;  // 0..4095
        int which = id >> 10;
        int rem = id & 1023;
        int k = rem >> 2, h = rem & 3;
        float s = 0.f;
        if (which == 0) {
            for (int d = 0; d < 64; ++d) s += ld1(W1s, k * 256 + h * 64 + d, f32m) * ld1(al1, h * 64 + d, f32m);
            wl1[k * 4 + h] = s;
        } else if (which == 1) {
            for (int d = 0; d < 64; ++d) s += ld1(W1d, k * 256 + h * 64 + d, f32m) * ld1(ar1, h * 64 + d, f32m);
            wr1[k * 4 + h] = s;
        } else if (which == 2) {
            for (int d = 0; d < 32; ++d) s += ld1(W2s, k * 128 + h * 32 + d, f32m) * ld1(al2, h * 32 + d, f32m);
            wl2[k * 4 + h] = s;
        } else {
            for (int d = 0; d < 32; ++d) s += ld1(W2d, k * 128 + h * 32 + d, f32m) * ld1(ar2, h * 32 + d, f32m);
            wr2[k * 4 + h] = s;
        }
    }
}

// ---- device helpers for fused stage B ----
__device__ void dev_scan(const int* __restrict__ deg, int* __restrict__ rowptr,
                         int* __restrict__ cursor) {
    // one block, 256 threads; thread t owns chunk [t*196, t*196+196)
    __shared__ int sm[256];
    int t = threadIdx.x;
    int base = t * 196;
    int cnt = base < NN ? min(196, NN - base) : 0;
    int sum = 0;
    for (int i = 0; i < cnt; ++i) sum += deg[base + i];
    int x = sum;
    sm[t] = x;
    __syncthreads();
    for (int off = 1; off < 256; off <<= 1) {
        int y = (t >= off) ? sm[t - off] : 0;
        __syncthreads();
        x += y;
        sm[t] = x;
        __syncthreads();
    }
    int run = x - sum;  // exclusive prefix
    for (int i = 0; i < cnt; ++i) {
        int d = deg[base + i];
        rowptr[base + i] = run;
        cursor[base + i] = run;
        run += d;
    }
    if (t == 255) rowptr[NN] = EE;
}

__device__ void dev_eler(const void* __restrict__ X, bool f32m, int node,
                         const float* __restrict__ wl, const float* __restrict__ wr,
                         float* __restrict__ el, float* __restrict__ er) {
    int lane = threadIdx.x & 63;
    float a[4];
    load4(X, (size_t)node * 64 + lane, f32m, a);
    float accl[4] = {0, 0, 0, 0}, accr[4] = {0, 0, 0, 0};
    int k0 = lane * 4;
#pragma unroll
    for (int j = 0; j < 4; ++j) {
        float4 wlv = ((const float4*)wl)[k0 + j];
        float4 wrv = ((const float4*)wr)[k0 + j];
        accl[0] += a[j] * wlv.x; accl[1] += a[j] * wlv.y;
        accl[2] += a[j] * wlv.z; accl[3] += a[j] * wlv.w;
        accr[0] += a[j] * wrv.x; accr[1] += a[j] * wrv.y;
        accr[2] += a[j] * wrv.z; accr[3] += a[j] * wrv.w;
    }
#pragma unroll
    for (int off = 32; off > 0; off >>= 1) {
#pragma unroll
        for (int t = 0; t < 4; ++t) {
            accl[t] += __shfl_down(accl[t], off, 64);
            accr[t] += __shfl_down(accr[t], off, 64);
        }
    }
    if (lane == 0) {
        float4 vl = {accl[0], accl[1], accl[2], accl[3]};
        float4 vr = {accr[0], accr[1], accr[2], accr[3]};
        ((float4*)el)[node] = vl;
        ((float4*)er)[node] = vr;
    }
}

__device__ void dev_gemm(const void* __restrict__ A, bool af32, int bid2,
                         const u16* __restrict__ BT, u16* __restrict__ C) {
    __shared__ u16 At[128 * 72];
    __shared__ u16 Bt[128 * 72];
    int t = threadIdx.x;
    int lane = t & 63, w = t >> 6;
    int mt = bid2 >> 1, nt = bid2 & 1;
    int m0 = mt * 128, n0 = nt * 128;
    int wr = (w >> 1) * 64, wc = (w & 1) * 64;
    f32x4 acc[4][4] = {};
    int q = lane >> 4, cl = lane & 15;

    for (int ph = 0; ph < 4; ++ph) {
        int kb = ph * 64;
        for (int it = 0; it < 4; ++it) {
            int c = it * 256 + t;
            int row = c >> 3, c8 = c & 7;
            int rowg = m0 + row;
            if (af32) {
                if (rowg < NN) {
                    const float* ap = (const float*)A + (size_t)rowg * 256 + kb + c8 * 8;
                    float4 v0 = ((const float4*)ap)[0];
                    float4 v1 = ((const float4*)ap)[1];
                    ushort4 lo = {f2bf(v0.x), f2bf(v0.y), f2bf(v0.z), f2bf(v0.w)};
                    ushort4 hi = {f2bf(v1.x), f2bf(v1.y), f2bf(v1.z), f2bf(v1.w)};
                    *(ushort4*)&At[row * 72 + c8 * 8] = lo;
                    *(ushort4*)&At[row * 72 + c8 * 8 + 4] = hi;
                } else {
                    ushort4 z = {0, 0, 0, 0};
                    *(ushort4*)&At[row * 72 + c8 * 8] = z;
                    *(ushort4*)&At[row * 72 + c8 * 8 + 4] = z;
                }
            } else {
                float4 av;
                if (rowg < NN) {
                    av = *(const float4*)((const u16*)A + (size_t)rowg * 256 + kb + c8 * 8);
                } else {
                    av = make_float4(0.f, 0.f, 0.f, 0.f);
                }
                *(float4*)&At[row * 72 + c8 * 8] = av;
            }
            float4 bv = *(const float4*)(BT + (size_t)(n0 + row) * 256 + kb + c8 * 8);
            *(float4*)&Bt[row * 72 + c8 * 8] = bv;
        }
        __syncthreads();
#pragma unroll
        for (int ks = 0; ks < 2; ++ks) {
            short8 af[4], bf[4];
#pragma unroll
            for (int i = 0; i < 4; ++i)
                af[i] = *(const short8*)&At[(wr + i * 16 + cl) * 72 + ks * 32 + q * 8];
#pragma unroll
            for (int j = 0; j < 4; ++j)
                bf[j] = *(const short8*)&Bt[(wc + j * 16 + cl) * 72 + ks * 32 + q * 8];
#pragma unroll
            for (int i = 0; i < 4; ++i)
#pragma unroll
                for (int j = 0; j < 4; ++j)
                    acc[i][j] = __builtin_amdgcn_mfma_f32_16x16x32_bf16(af[i], bf[j], acc[i][j], 0, 0, 0);
        }
        __syncthreads();
    }
#pragma unroll
    for (int i = 0; i < 4; ++i)
#pragma unroll
        for (int j = 0; j < 4; ++j)
#pragma unroll
            for (int r = 0; r < 4; ++r) {
                int mrow = m0 + wr + i * 16 + q * 4 + r;
                if (mrow < NN)
                    C[(size_t)mrow * 256 + n0 + wc + j * 16 + cl] = f2bf(acc[i][j][r]);
            }
}

// ---- fused stage B: [0] CSR scan | [1..12500] eler1 | [12501..13282] gemm1 ----
__global__ void k_stageB(const void* __restrict__ h, const int* __restrict__ mode,
                         const int* __restrict__ deg, int* __restrict__ rowptr,
                         int* __restrict__ cursor,
                         const float* __restrict__ wl1, const float* __restrict__ wr1,
                         float* __restrict__ el1, float* __restrict__ er1,
                         const u16* __restrict__ BT1, u16* __restrict__ fs1) {
    int bid = blockIdx.x;
    if (bid == 0) {
        dev_scan(deg, rowptr, cursor);
    } else if (bid <= 12500) {
        bool f32m = (*mode) != 0;
        int node = (bid - 1) * 4 + (threadIdx.x >> 6);
        dev_eler(h, f32m, node, wl1, wr1, el1, er1);
    } else {
        bool af32 = (*mode) != 0;
        dev_gemm(h, af32, bid - 12501, BT1, fs1);
    }
}

__global__ void k_scatter(const int* __restrict__ src, const int* __restrict__ dst,
                          int* __restrict__ cursor, int* __restrict__ csrc) {
    int e = blockIdx.x * 256 + threadIdx.x;
    if (e < EE) {
        int d = dst[e];
        int slot = atomicAdd(&cursor[d], 1);
        csrc[slot] = src[e];
    }
}

// ---- layer-2 GEMM standalone ----
__global__ void k_gemm2(const void* __restrict__ A, const u16* __restrict__ BT,
                        u16* __restrict__ C) {
    dev_gemm(A, false, blockIdx.x, BT, C);
}

// ---- layer-1 aggregation (single-pass no-max softmax) + fused eler2 ----
__global__ void k_agg1(const int* __restrict__ rowptr, const int* __restrict__ csrc,
                       const float* __restrict__ el, const float* __restrict__ er,
                       const u16* __restrict__ fs, const void* __restrict__ h_in,
                       u16* __restrict__ h1,
                       const float* __restrict__ wl2, const float* __restrict__ wr2,
                       float* __restrict__ el2, float* __restrict__ er2,
                       const int* __restrict__ mode) {
    bool f32m = (*mode) != 0;
    int wave = threadIdx.x >> 6, lane = threadIdx.x & 63;
    int node = blockIdx.x * 4 + wave;
    int beg = rowptr[node], end = rowptr[node + 1];
    int head = lane >> 4;
    float erh = er[node * 4 + head];
    float a0 = 0.f, a1 = 0.f, a2 = 0.f, a3 = 0.f, ll = 0.f;
#pragma unroll 2
    for (int p = beg; p < end; ++p) {
        int s = csrc[p];
        float e = el[s * 4 + head] + erh;
        e = e > 0.f ? e : 0.2f * e;
        e = fminf(fmaxf(e, -60.f), 60.f);
        float pw = __expf(e);
        ushort4 fv = *(const ushort4*)(fs + (size_t)s * 256 + lane * 4);
        ll += pw;
        a0 += pw * bf2f(fv.x);
        a1 += pw * bf2f(fv.y);
        a2 += pw * bf2f(fv.z);
        a3 += pw * bf2f(fv.w);
    }
    float rinv = 1.f / ll;
    float res[4];
    load4(h_in, (size_t)node * 64 + lane, f32m, res);
    float v0 = a0 * rinv + res[0], v1 = a1 * rinv + res[1];
    float v2 = a2 * rinv + res[2], v3 = a3 * rinv + res[3];
    v0 = v0 > 0.f ? v0 : __expf(v0) - 1.f;
    v1 = v1 > 0.f ? v1 : __expf(v1) - 1.f;
    v2 = v2 > 0.f ? v2 : __expf(v2) - 1.f;
    v3 = v3 > 0.f ? v3 : __expf(v3) - 1.f;
    ushort4 o = {f2bf(v0), f2bf(v1), f2bf(v2), f2bf(v3)};
    ((ushort4*)h1)[(size_t)node * 64 + lane] = o;
    // fused eler2: lane owns h1 cols lane*4..+3
    float4 w0 = ((const float4*)wl2)[lane * 4 + 0];
    float4 w1 = ((const float4*)wl2)[lane * 4 + 1];
    float4 w2 = ((const float4*)wl2)[lane * 4 + 2];
    float4 w3 = ((const float4*)wl2)[lane * 4 + 3];
    float4 r0 = ((const float4*)wr2)[lane * 4 + 0];
    float4 r1 = ((const float4*)wr2)[lane * 4 + 1];
    float4 r2 = ((const float4*)wr2)[lane * 4 + 2];
    float4 r3 = ((const float4*)wr2)[lane * 4 + 3];
    float acl[4], acr[4];
    acl[0] = v0 * w0.x + v1 * w1.x + v2 * w2.x + v3 * w3.x;
    acl[1] = v0 * w0.y + v1 * w1.y + v2 * w2.y + v3 * w3.y;
    acl[2] = v0 * w0.z + v1 * w1.z + v2 * w2.z + v3 * w3.z;
    acl[3] = v0 * w0.w + v1 * w1.w + v2 * w2.w + v3 * w3.w;
    acr[0] = v0 * r0.x + v1 * r1.x + v2 * r2.x + v3 * r3.x;
    acr[1] = v0 * r0.y + v1 * r1.y + v2 * r2.y + v3 * r3.y;
    acr[2] = v0 * r0.z + v1 * r1.z + v2 * r2.z + v3 * r3.z;
    acr[3] = v0 * r0.w + v1 * r1.w + v2 * r2.w + v3 * r3.w;
#pragma unroll
    for (int off = 32; off > 0; off >>= 1) {
#pragma unroll
        for (int t = 0; t < 4; ++t) {
            acl[t] += __shfl_down(acl[t], off, 64);
            acr[t] += __shfl_down(acr[t], off, 64);
        }
    }
    if (lane == 0) {
        float4 vl = {acl[0], acl[1], acl[2], acl[3]};
        float4 vr = {acr[0], acr[1], acr[2], acr[3]};
        ((float4*)el2)[node] = vl;
        ((float4*)er2)[node] = vr;
    }
}

// ---- layer-2 aggregation + residual + head-mean ----
__global__ void k_agg2(const int* __restrict__ rowptr, const int* __restrict__ csrc,
                       const float* __restrict__ el, const float* __restrict__ er,
                       const u16* __restrict__ c2, void* __restrict__ out,
                       const int* __restrict__ mode) {
    bool f32m = (*mode) != 0;
    int wave = threadIdx.x >> 6, lane = threadIdx.x & 63;
    int node = blockIdx.x * 4 + wave;
    int beg = rowptr[node], end = rowptr[node + 1];
    int head = lane >> 4;
    float erh = er[node * 4 + head];
    float a0 = 0.f, a1 = 0.f, ll = 0.f;
#pragma unroll 2
    for (int p = beg; p < end; ++p) {
        int s = csrc[p];
        float e = el[s * 4 + head] + erh;
        e = e > 0.f ? e : 0.2f * e;
        e = fminf(fmaxf(e, -60.f), 60.f);
        float pw = __expf(e);
        ushort2 fv = *(const ushort2*)(c2 + (size_t)s * 256 + lane * 2);
        ll += pw;
        a0 += pw * bf2f(fv.x);
        a1 += pw * bf2f(fv.y);
    }
    float rinv = 1.f / ll;
    ushort2 rv = *(const ushort2*)(c2 + (size_t)node * 256 + 128 + lane * 2);
    float o0 = a0 * rinv + bf2f(rv.x);
    float o1 = a1 * rinv + bf2f(rv.y);
    o0 += __shfl_xor(o0, 16, 64); o0 += __shfl_xor(o0, 32, 64);
    o1 += __shfl_xor(o1, 16, 64); o1 += __shfl_xor(o1, 32, 64);
    if (lane < 16) {
        float v0 = 0.25f * o0, v1 = 0.25f * o1;
        size_t oi = (size_t)node * 32 + lane * 2;
        if (f32m) {
            ((float*)out)[oi] = v0;
            ((float*)out)[oi + 1] = v1;
        } else {
            ushort2 ov = {f2bf(v0), f2bf(v1)};
            *(ushort2*)((u16*)out + oi) = ov;
        }
    }
}

extern "C" void kernel_launch(void* const* d_in, const int* in_sizes, int n_in,
                              void* d_out, int out_size, void* d_ws, size_t ws_size,
                              hipStream_t stream) {
    int ih = 0, isrc = 1, idst = 2, iW1s = 3, iW1d = 4, ial1 = 5, iar1 = 6,
        iW2s = 7, iW2d = 8, ial2 = 9, iar2 = 10, iWres = 11;
    if (n_in >= 12 && in_sizes[0] != 12800000) {
        iW1d = 0; iW1s = 1; iW2d = 2; iW2s = 3; iWres = 4; ial1 = 5; ial2 = 6;
        iar1 = 7; iar2 = 8; idst = 9; ih = 10; isrc = 11;
    }
    const void* h     = d_in[ih];
    const int* src    = (const int*)d_in[isrc];
    const int* dst    = (const int*)d_in[idst];
    const void* W1s   = d_in[iW1s];
    const void* W1d   = d_in[iW1d];
    const void* al1   = d_in[ial1];
    const void* ar1   = d_in[iar1];
    const void* W2s   = d_in[iW2s];
    const void* W2d   = d_in[iW2d];
    const void* al2   = d_in[ial2];
    const void* ar2   = d_in[iar2];
    const void* Wres2 = d_in[iWres];

    char* w = (char*)d_ws;
    size_t off = 0;
    auto alloc = [&](size_t bytes) -> void* {
        void* p = w + off;
        off += (bytes + 255) & ~(size_t)255;
        return p;
    };
    int* mode   = (int*)alloc(256);
    float* wl1 = (float*)alloc(256 * 4 * 4);
    float* wr1 = (float*)alloc(256 * 4 * 4);
    float* wl2 = (float*)alloc(256 * 4 * 4);
    float* wr2 = (float*)alloc(256 * 4 * 4);
    int* deg    = (int*)alloc(NN * 4);
    int* cursor = (int*)alloc(NN * 4);
    int* rowptr = (int*)alloc((NN + 1) * 4);
    int* csrc   = (int*)alloc((size_t)EE * 4);
    float* el1  = (float*)alloc((size_t)NN * 4 * 4);
    float* er1  = (float*)alloc((size_t)NN * 4 * 4);
    float* el2  = (float*)alloc((size_t)NN * 4 * 4);
    float* er2  = (float*)alloc((size_t)NN * 4 * 4);
    u16* BT1    = (u16*)alloc(256 * 256 * 2);
    u16* BT2    = (u16*)alloc(256 * 256 * 2);
    u16* fs1    = (u16*)alloc((size_t)NN * 256 * 2);   // 25.6 MB
    u16* h1     = (u16*)alloc((size_t)NN * 256 * 2);   // 25.6 MB
    u16* c2     = fs1;   // fs1 dead after k_agg1; c2 = [fs2 | res2]

    // 1: detect + zero deg
    k_detect<<<197, 256, 0, stream>>>((const u16*)h, mode, deg);
    // 2: B-transpose + attn vecs + deg count
    k_prep<<<528 + (EE + 255) / 256, 256, 0, stream>>>(
        W1s, al1, W1d, ar1, W2s, al2, W2d, ar2, Wres2, dst,
        BT1, BT2, wl1, wr1, wl2, wr2, deg, mode);
    // 3: CSR scan | eler1 | gemm1 (independent, fused into one dispatch)
    k_stageB<<<12501 + 782, 256, 0, stream>>>(h, mode, deg, rowptr, cursor,
                                              wl1, wr1, el1, er1, BT1, fs1);
    // 4: edge scatter
    k_scatter<<<(EE + 255) / 256, 256, 0, stream>>>(src, dst, cursor, csrc);
    // 5: layer-1 aggregation + fused eler2
    k_agg1<<<NN / 4, 256, 0, stream>>>(rowptr, csrc, el1, er1, fs1, h, h1,
                                       wl2, wr2, el2, er2, mode);
    // 6: layer-2 fused GEMM [W2s | Wres2]
    k_gemm2<<<782, 256, 0, stream>>>(h1, BT2, c2);
    // 7: layer-2 aggregation + residual + head-mean
    k_agg2<<<NN / 4, 256, 0, stream>>>(rowptr, csrc, el2, er2, c2, d_out, mode);
}

// Round 9
// 527.256 us; speedup vs baseline: 1.0414x; 1.0414x over previous
//
#include <hip/hip_runtime.h>
#include <hip/hip_bf16.h>

#define NN 50000
#define EE 850000

typedef unsigned short u16;
using short8 = __attribute__((ext_vector_type(8))) short;
using f32x4  = __attribute__((ext_vector_type(4))) float;

__device__ __forceinline__ float bf2f(u16 u) {
    union { unsigned int i; float f; } v; v.i = ((unsigned int)u) << 16; return v.f;
}
__device__ __forceinline__ u16 f2bf(float f) {
    __hip_bfloat16 h = __float2bfloat16(f);
    return *reinterpret_cast<u16*>(&h);
}

__device__ __forceinline__ float ld1(const void* X, size_t i, bool f32m) {
    return f32m ? ((const float*)X)[i] : bf2f(((const u16*)X)[i]);
}
__device__ __forceinline__ void load4(const void* X, size_t g, bool f32m, float o[4]) {
    if (f32m) {
        float4 v = ((const float4*)X)[g];
        o[0] = v.x; o[1] = v.y; o[2] = v.z; o[3] = v.w;
    } else {
        ushort4 v = ((const ushort4*)X)[g];
        o[0] = bf2f(v.x); o[1] = bf2f(v.y); o[2] = bf2f(v.z); o[3] = bf2f(v.w);
    }
}

// ---- block 0: dtype detect; blocks 1..196: zero deg ----
__global__ void k_detect(const u16* __restrict__ hh, int* __restrict__ flag,
                         int* __restrict__ deg) {
    if (blockIdx.x != 0) {
        int i = (blockIdx.x - 1) * 256 + threadIdx.x;
        if (i < NN) deg[i] = 0;
        return;
    }
    __shared__ int sm[256];
    int t = threadIdx.x;
    int c = 0;
    for (int i = 0; i < 16; ++i) {
        u16 u = hh[t * 16 + i];
        int e = (u >> 7) & 0xFF;
        if (e != 0 && (e < 90 || e > 160)) ++c;
    }
    sm[t] = c;
    __syncthreads();
    for (int s = 128; s > 0; s >>= 1) {
        if (t < s) sm[t] += sm[t + s];
        __syncthreads();
    }
    if (t == 0) *flag = (sm[0] > 200) ? 1 : 0;
}

// ---- fused prep: 0..511 B-transpose, 512..527 attn vecs, rest deg count ----
__global__ void k_prep(const void* __restrict__ W1s, const void* __restrict__ al1,
                       const void* __restrict__ W1d, const void* __restrict__ ar1,
                       const void* __restrict__ W2s, const void* __restrict__ al2,
                       const void* __restrict__ W2d, const void* __restrict__ ar2,
                       const void* __restrict__ Wres2, const int* __restrict__ dst,
                       u16* __restrict__ BT1, u16* __restrict__ BT2,
                       float* __restrict__ wl1, float* __restrict__ wr1,
                       float* __restrict__ wl2, float* __restrict__ wr2,
                       int* __restrict__ deg, const int* __restrict__ mode) {
    int bid = blockIdx.x;
    if (bid >= 528) {
        int e = (bid - 528) * 256 + threadIdx.x;
        if (e < EE) atomicAdd(&deg[dst[e]], 1);
        return;
    }
    bool f32m = (*mode) != 0;
    if (bid < 512) {
        int id = bid * 256 + threadIdx.x;  // 0..131071
        int which = id >> 16;
        int rem = id & 65535;
        int n = rem >> 8, k = rem & 255;
        if (which == 0) {
            BT1[n * 256 + k] = f2bf(ld1(W1s, (size_t)k * 256 + n, f32m));
        } else {
            float v = (n < 128) ? ld1(W2s, (size_t)k * 128 + n, f32m)
                                : ld1(Wres2, (size_t)k * 128 + (n - 128), f32m);
            BT2[n * 256 + k] = f2bf(v);
        }
    } else {
        int id = (bid - 512) * 256 + threadIdx.x;  // 0..4095
        int which = id >> 10;
        int rem = id & 1023;
        int k = rem >> 2, h = rem & 3;
        float s = 0.f;
        if (which == 0) {
            for (int d = 0; d < 64; ++d) s += ld1(W1s, k * 256 + h * 64 + d, f32m) * ld1(al1, h * 64 + d, f32m);
            wl1[k * 4 + h] = s;
        } else if (which == 1) {
            for (int d = 0; d < 64; ++d) s += ld1(W1d, k * 256 + h * 64 + d, f32m) * ld1(ar1, h * 64 + d, f32m);
            wr1[k * 4 + h] = s;
        } else if (which == 2) {
            for (int d = 0; d < 32; ++d) s += ld1(W2s, k * 128 + h * 32 + d, f32m) * ld1(al2, h * 32 + d, f32m);
            wl2[k * 4 + h] = s;
        } else {
            for (int d = 0; d < 32; ++d) s += ld1(W2d, k * 128 + h * 32 + d, f32m) * ld1(ar2, h * 32 + d, f32m);
            wr2[k * 4 + h] = s;
        }
    }
}

// ---- single-block CSR scan (replaces scan1/scan2/scan3) ----
__global__ void k_scan(const int* __restrict__ deg, int* __restrict__ rowptr,
                       int* __restrict__ cursor) {
    __shared__ int sm[256];
    int t = threadIdx.x;
    int base = t * 196;
    int cnt = base < NN ? min(196, NN - base) : 0;
    int sum = 0;
    for (int i = 0; i < cnt; ++i) sum += deg[base + i];
    int x = sum;
    sm[t] = x;
    __syncthreads();
    for (int off = 1; off < 256; off <<= 1) {
        int y = (t >= off) ? sm[t - off] : 0;
        __syncthreads();
        x += y;
        sm[t] = x;
        __syncthreads();
    }
    int run = x - sum;  // exclusive prefix
    for (int i = 0; i < cnt; ++i) {
        int d = deg[base + i];
        rowptr[base + i] = run;
        cursor[base + i] = run;
        run += d;
    }
    if (t == 255) rowptr[NN] = EE;
}

__global__ void k_scatter(const int* __restrict__ src, const int* __restrict__ dst,
                          int* __restrict__ cursor, int* __restrict__ csrc) {
    int e = blockIdx.x * 256 + threadIdx.x;
    if (e < EE) {
        int d = dst[e];
        int slot = atomicAdd(&cursor[d], 1);
        csrc[slot] = src[e];
    }
}

// ---- el/er: el[node][4] = sum_k X[node][k]*wl[k][h]  (float4 per node) ----
__global__ void k_eler(const void* __restrict__ X,
                       const float* __restrict__ wl, const float* __restrict__ wr,
                       float* __restrict__ el, float* __restrict__ er,
                       const int* __restrict__ mode) {
    bool f32m = (*mode) != 0;
    int wave = threadIdx.x >> 6, lane = threadIdx.x & 63;
    int node = blockIdx.x * 4 + wave;
    float a[4];
    load4(X, (size_t)node * 64 + lane, f32m, a);
    float accl[4] = {0, 0, 0, 0}, accr[4] = {0, 0, 0, 0};
    int k0 = lane * 4;
#pragma unroll
    for (int j = 0; j < 4; ++j) {
        float4 wlv = ((const float4*)wl)[k0 + j];
        float4 wrv = ((const float4*)wr)[k0 + j];
        accl[0] += a[j] * wlv.x; accl[1] += a[j] * wlv.y;
        accl[2] += a[j] * wlv.z; accl[3] += a[j] * wlv.w;
        accr[0] += a[j] * wrv.x; accr[1] += a[j] * wrv.y;
        accr[2] += a[j] * wrv.z; accr[3] += a[j] * wrv.w;
    }
#pragma unroll
    for (int off = 32; off > 0; off >>= 1) {
#pragma unroll
        for (int t = 0; t < 4; ++t) {
            accl[t] += __shfl_down(accl[t], off, 64);
            accr[t] += __shfl_down(accr[t], off, 64);
        }
    }
    if (lane == 0) {
        float4 vl = {accl[0], accl[1], accl[2], accl[3]};
        float4 vr = {accr[0], accr[1], accr[2], accr[3]};
        ((float4*)el)[node] = vl;
        ((float4*)er)[node] = vr;
    }
}

// ---- MFMA GEMM: C[M][256] bf16 = A[M][256] @ B (BT transposed [256n][256k]) ----
// 128x128 C-tile per block (4 waves, 2x2); BK=64, 4 phases. LDS pad 72 u16/row.
__global__ void k_gemm_mfma(const void* __restrict__ A, int aDual,
                            const u16* __restrict__ BT, u16* __restrict__ C,
                            const int* __restrict__ mode) {
    bool af32 = aDual && ((*mode) != 0);
    __shared__ u16 At[128 * 72];
    __shared__ u16 Bt[128 * 72];
    int t = threadIdx.x;
    int lane = t & 63, w = t >> 6;
    int mt = blockIdx.x >> 1, nt = blockIdx.x & 1;
    int m0 = mt * 128, n0 = nt * 128;
    int wr = (w >> 1) * 64, wc = (w & 1) * 64;
    f32x4 acc[4][4] = {};
    int q = lane >> 4, cl = lane & 15;

    for (int ph = 0; ph < 4; ++ph) {
        int kb = ph * 64;
        for (int it = 0; it < 4; ++it) {
            int c = it * 256 + t;
            int row = c >> 3, c8 = c & 7;
            int rowg = m0 + row;
            if (af32) {
                if (rowg < NN) {
                    const float* ap = (const float*)A + (size_t)rowg * 256 + kb + c8 * 8;
                    float4 v0 = ((const float4*)ap)[0];
                    float4 v1 = ((const float4*)ap)[1];
                    ushort4 lo = {f2bf(v0.x), f2bf(v0.y), f2bf(v0.z), f2bf(v0.w)};
                    ushort4 hi = {f2bf(v1.x), f2bf(v1.y), f2bf(v1.z), f2bf(v1.w)};
                    *(ushort4*)&At[row * 72 + c8 * 8] = lo;
                    *(ushort4*)&At[row * 72 + c8 * 8 + 4] = hi;
                } else {
                    ushort4 z = {0, 0, 0, 0};
                    *(ushort4*)&At[row * 72 + c8 * 8] = z;
                    *(ushort4*)&At[row * 72 + c8 * 8 + 4] = z;
                }
            } else {
                float4 av;
                if (rowg < NN) {
                    av = *(const float4*)((const u16*)A + (size_t)rowg * 256 + kb + c8 * 8);
                } else {
                    av = make_float4(0.f, 0.f, 0.f, 0.f);
                }
                *(float4*)&At[row * 72 + c8 * 8] = av;
            }
            float4 bv = *(const float4*)(BT + (size_t)(n0 + row) * 256 + kb + c8 * 8);
            *(float4*)&Bt[row * 72 + c8 * 8] = bv;
        }
        __syncthreads();
#pragma unroll
        for (int ks = 0; ks < 2; ++ks) {
            short8 af[4], bf[4];
#pragma unroll
            for (int i = 0; i < 4; ++i)
                af[i] = *(const short8*)&At[(wr + i * 16 + cl) * 72 + ks * 32 + q * 8];
#pragma unroll
            for (int j = 0; j < 4; ++j)
                bf[j] = *(const short8*)&Bt[(wc + j * 16 + cl) * 72 + ks * 32 + q * 8];
#pragma unroll
            for (int i = 0; i < 4; ++i)
#pragma unroll
                for (int j = 0; j < 4; ++j)
                    acc[i][j] = __builtin_amdgcn_mfma_f32_16x16x32_bf16(af[i], bf[j], acc[i][j], 0, 0, 0);
        }
        __syncthreads();
    }
#pragma unroll
    for (int i = 0; i < 4; ++i)
#pragma unroll
        for (int j = 0; j < 4; ++j)
#pragma unroll
            for (int r = 0; r < 4; ++r) {
                int mrow = m0 + wr + i * 16 + q * 4 + r;
                if (mrow < NN)
                    C[(size_t)mrow * 256 + n0 + wc + j * 16 + cl] = f2bf(acc[i][j][r]);
            }
}

// ---- layer-1 aggregation (single-pass no-max softmax) + fused eler2 ----
__global__ void k_agg1(const int* __restrict__ rowptr, const int* __restrict__ csrc,
                       const float* __restrict__ el, const float* __restrict__ er,
                       const u16* __restrict__ fs, const void* __restrict__ h_in,
                       u16* __restrict__ h1,
                       const float* __restrict__ wl2, const float* __restrict__ wr2,
                       float* __restrict__ el2, float* __restrict__ er2,
                       const int* __restrict__ mode) {
    bool f32m = (*mode) != 0;
    int wave = threadIdx.x >> 6, lane = threadIdx.x & 63;
    int node = blockIdx.x * 4 + wave;
    int beg = rowptr[node], end = rowptr[node + 1];
    int head = lane >> 4;
    float erh = er[node * 4 + head];
    float a0 = 0.f, a1 = 0.f, a2 = 0.f, a3 = 0.f, ll = 0.f;
#pragma unroll 2
    for (int p = beg; p < end; ++p) {
        int s = csrc[p];
        float e = el[s * 4 + head] + erh;
        e = e > 0.f ? e : 0.2f * e;
        e = fminf(fmaxf(e, -60.f), 60.f);
        float pw = __expf(e);
        ushort4 fv = *(const ushort4*)(fs + (size_t)s * 256 + lane * 4);
        ll += pw;
        a0 += pw * bf2f(fv.x);
        a1 += pw * bf2f(fv.y);
        a2 += pw * bf2f(fv.z);
        a3 += pw * bf2f(fv.w);
    }
    float rinv = 1.f / ll;
    float res[4];
    load4(h_in, (size_t)node * 64 + lane, f32m, res);
    float v0 = a0 * rinv + res[0], v1 = a1 * rinv + res[1];
    float v2 = a2 * rinv + res[2], v3 = a3 * rinv + res[3];
    v0 = v0 > 0.f ? v0 : __expf(v0) - 1.f;
    v1 = v1 > 0.f ? v1 : __expf(v1) - 1.f;
    v2 = v2 > 0.f ? v2 : __expf(v2) - 1.f;
    v3 = v3 > 0.f ? v3 : __expf(v3) - 1.f;
    ushort4 o = {f2bf(v0), f2bf(v1), f2bf(v2), f2bf(v3)};
    ((ushort4*)h1)[(size_t)node * 64 + lane] = o;
    // fused eler2: lane owns h1 cols lane*4..+3
    float4 w0 = ((const float4*)wl2)[lane * 4 + 0];
    float4 w1 = ((const float4*)wl2)[lane * 4 + 1];
    float4 w2 = ((const float4*)wl2)[lane * 4 + 2];
    float4 w3 = ((const float4*)wl2)[lane * 4 + 3];
    float4 r0 = ((const float4*)wr2)[lane * 4 + 0];
    float4 r1 = ((const float4*)wr2)[lane * 4 + 1];
    float4 r2 = ((const float4*)wr2)[lane * 4 + 2];
    float4 r3 = ((const float4*)wr2)[lane * 4 + 3];
    float acl[4], acr[4];
    acl[0] = v0 * w0.x + v1 * w1.x + v2 * w2.x + v3 * w3.x;
    acl[1] = v0 * w0.y + v1 * w1.y + v2 * w2.y + v3 * w3.y;
    acl[2] = v0 * w0.z + v1 * w1.z + v2 * w2.z + v3 * w3.z;
    acl[3] = v0 * w0.w + v1 * w1.w + v2 * w2.w + v3 * w3.w;
    acr[0] = v0 * r0.x + v1 * r1.x + v2 * r2.x + v3 * r3.x;
    acr[1] = v0 * r0.y + v1 * r1.y + v2 * r2.y + v3 * r3.y;
    acr[2] = v0 * r0.z + v1 * r1.z + v2 * r2.z + v3 * r3.z;
    acr[3] = v0 * r0.w + v1 * r1.w + v2 * r2.w + v3 * r3.w;
#pragma unroll
    for (int off = 32; off > 0; off >>= 1) {
#pragma unroll
        for (int t = 0; t < 4; ++t) {
            acl[t] += __shfl_down(acl[t], off, 64);
            acr[t] += __shfl_down(acr[t], off, 64);
        }
    }
    if (lane == 0) {
        float4 vl = {acl[0], acl[1], acl[2], acl[3]};
        float4 vr = {acr[0], acr[1], acr[2], acr[3]};
        ((float4*)el2)[node] = vl;
        ((float4*)er2)[node] = vr;
    }
}

// ---- layer-2 aggregation + residual + head-mean ----
// c2 layout: [node][256]: cols 0..127 = fs2 (h*32+d), cols 128..255 = res2
__global__ void k_agg2(const int* __restrict__ rowptr, const int* __restrict__ csrc,
                       const float* __restrict__ el, const float* __restrict__ er,
                       const u16* __restrict__ c2, void* __restrict__ out,
                       const int* __restrict__ mode) {
    bool f32m = (*mode) != 0;
    int wave = threadIdx.x >> 6, lane = threadIdx.x & 63;
    int node = blockIdx.x * 4 + wave;
    int beg = rowptr[node], end = rowptr[node + 1];
    int head = lane >> 4;
    float erh = er[node * 4 + head];
    float a0 = 0.f, a1 = 0.f, ll = 0.f;
#pragma unroll 2
    for (int p = beg; p < end; ++p) {
        int s = csrc[p];
        float e = el[s * 4 + head] + erh;
        e = e > 0.f ? e : 0.2f * e;
        e = fminf(fmaxf(e, -60.f), 60.f);
        float pw = __expf(e);
        ushort2 fv = *(const ushort2*)(c2 + (size_t)s * 256 + lane * 2);
        ll += pw;
        a0 += pw * bf2f(fv.x);
        a1 += pw * bf2f(fv.y);
    }
    float rinv = 1.f / ll;
    ushort2 rv = *(const ushort2*)(c2 + (size_t)node * 256 + 128 + lane * 2);
    float o0 = a0 * rinv + bf2f(rv.x);
    float o1 = a1 * rinv + bf2f(rv.y);
    o0 += __shfl_xor(o0, 16, 64); o0 += __shfl_xor(o0, 32, 64);
    o1 += __shfl_xor(o1, 16, 64); o1 += __shfl_xor(o1, 32, 64);
    if (lane < 16) {
        float v0 = 0.25f * o0, v1 = 0.25f * o1;
        size_t oi = (size_t)node * 32 + lane * 2;
        if (f32m) {
            ((float*)out)[oi] = v0;
            ((float*)out)[oi + 1] = v1;
        } else {
            ushort2 ov = {f2bf(v0), f2bf(v1)};
            *(ushort2*)((u16*)out + oi) = ov;
        }
    }
}

extern "C" void kernel_launch(void* const* d_in, const int* in_sizes, int n_in,
                              void* d_out, int out_size, void* d_ws, size_t ws_size,
                              hipStream_t stream) {
    int ih = 0, isrc = 1, idst = 2, iW1s = 3, iW1d = 4, ial1 = 5, iar1 = 6,
        iW2s = 7, iW2d = 8, ial2 = 9, iar2 = 10, iWres = 11;
    if (n_in >= 12 && in_sizes[0] != 12800000) {
        iW1d = 0; iW1s = 1; iW2d = 2; iW2s = 3; iWres = 4; ial1 = 5; ial2 = 6;
        iar1 = 7; iar2 = 8; idst = 9; ih = 10; isrc = 11;
    }
    const void* h     = d_in[ih];
    const int* src    = (const int*)d_in[isrc];
    const int* dst    = (const int*)d_in[idst];
    const void* W1s   = d_in[iW1s];
    const void* W1d   = d_in[iW1d];
    const void* al1   = d_in[ial1];
    const void* ar1   = d_in[iar1];
    const void* W2s   = d_in[iW2s];
    const void* W2d   = d_in[iW2d];
    const void* al2   = d_in[ial2];
    const void* ar2   = d_in[iar2];
    const void* Wres2 = d_in[iWres];

    char* w = (char*)d_ws;
    size_t off = 0;
    auto alloc = [&](size_t bytes) -> void* {
        void* p = w + off;
        off += (bytes + 255) & ~(size_t)255;
        return p;
    };
    int* mode   = (int*)alloc(256);
    float* wl1 = (float*)alloc(256 * 4 * 4);
    float* wr1 = (float*)alloc(256 * 4 * 4);
    float* wl2 = (float*)alloc(256 * 4 * 4);
    float* wr2 = (float*)alloc(256 * 4 * 4);
    int* deg    = (int*)alloc(NN * 4);
    int* cursor = (int*)alloc(NN * 4);
    int* rowptr = (int*)alloc((NN + 1) * 4);
    int* csrc   = (int*)alloc((size_t)EE * 4);
    float* el1  = (float*)alloc((size_t)NN * 4 * 4);
    float* er1  = (float*)alloc((size_t)NN * 4 * 4);
    float* el2  = (float*)alloc((size_t)NN * 4 * 4);
    float* er2  = (float*)alloc((size_t)NN * 4 * 4);
    u16* BT1    = (u16*)alloc(256 * 256 * 2);
    u16* BT2    = (u16*)alloc(256 * 256 * 2);
    u16* fs1    = (u16*)alloc((size_t)NN * 256 * 2);   // 25.6 MB
    u16* h1     = (u16*)alloc((size_t)NN * 256 * 2);   // 25.6 MB
    u16* c2     = fs1;   // fs1 dead after k_agg1; c2 = [fs2 | res2]

    // 1: detect + zero deg
    k_detect<<<197, 256, 0, stream>>>((const u16*)h, mode, deg);
    // 2: B-transpose + attn vecs + deg count
    k_prep<<<528 + (EE + 255) / 256, 256, 0, stream>>>(
        W1s, al1, W1d, ar1, W2s, al2, W2d, ar2, Wres2, dst,
        BT1, BT2, wl1, wr1, wl2, wr2, deg, mode);
    // 3: CSR scan (single block; replaces 3 scan dispatches)
    k_scan<<<1, 256, 0, stream>>>(deg, rowptr, cursor);
    // 4: edge scatter
    k_scatter<<<(EE + 255) / 256, 256, 0, stream>>>(src, dst, cursor, csrc);
    // 5: eler1
    k_eler<<<NN / 4, 256, 0, stream>>>(h, wl1, wr1, el1, er1, mode);
    // 6: layer-1 GEMM
    k_gemm_mfma<<<782, 256, 0, stream>>>(h, 1, BT1, fs1, mode);
    // 7: layer-1 aggregation + fused eler2
    k_agg1<<<NN / 4, 256, 0, stream>>>(rowptr, csrc, el1, er1, fs1, h, h1,
                                       wl2, wr2, el2, er2, mode);
    // 8: layer-2 fused GEMM [W2s | Wres2]
    k_gemm_mfma<<<782, 256, 0, stream>>>(h1, 0, BT2, c2, mode);
    // 9: layer-2 aggregation + residual + head-mean
    k_agg2<<<NN / 4, 256, 0, stream>>>(rowptr, csrc, el2, er2, c2, d_out, mode);
}

// Round 10
// 414.861 us; speedup vs baseline: 1.3235x; 1.2709x over previous
//
#include <hip/hip_runtime.h>
#include <hip/hip_bf16.h>

#define NN 50000
#define EE 850000
#define NBLK_SCAN 98  // ceil(50000/512)

typedef unsigned short u16;
using short8 = __attribute__((ext_vector_type(8))) short;
using f32x4  = __attribute__((ext_vector_type(4))) float;

__device__ __forceinline__ float bf2f(u16 u) {
    union { unsigned int i; float f; } v; v.i = ((unsigned int)u) << 16; return v.f;
}
__device__ __forceinline__ u16 f2bf(float f) {
    __hip_bfloat16 h = __float2bfloat16(f);
    return *reinterpret_cast<u16*>(&h);
}

__device__ __forceinline__ float ld1(const void* X, size_t i, bool f32m) {
    return f32m ? ((const float*)X)[i] : bf2f(((const u16*)X)[i]);
}
__device__ __forceinline__ void load4(const void* X, size_t g, bool f32m, float o[4]) {
    if (f32m) {
        float4 v = ((const float4*)X)[g];
        o[0] = v.x; o[1] = v.y; o[2] = v.z; o[3] = v.w;
    } else {
        ushort4 v = ((const ushort4*)X)[g];
        o[0] = bf2f(v.x); o[1] = bf2f(v.y); o[2] = bf2f(v.z); o[3] = bf2f(v.w);
    }
}

// ---- block 0: dtype detect; blocks 1..196: zero deg ----
__global__ void k_detect(const u16* __restrict__ hh, int* __restrict__ flag,
                         int* __restrict__ deg) {
    if (blockIdx.x != 0) {
        int i = (blockIdx.x - 1) * 256 + threadIdx.x;
        if (i < NN) deg[i] = 0;
        return;
    }
    __shared__ int sm[256];
    int t = threadIdx.x;
    int c = 0;
    for (int i = 0; i < 16; ++i) {
        u16 u = hh[t * 16 + i];
        int e = (u >> 7) & 0xFF;
        if (e != 0 && (e < 90 || e > 160)) ++c;
    }
    sm[t] = c;
    __syncthreads();
    for (int s = 128; s > 0; s >>= 1) {
        if (t < s) sm[t] += sm[t + s];
        __syncthreads();
    }
    if (t == 0) *flag = (sm[0] > 200) ? 1 : 0;
}

// ---- fused prep: 0..511 B-transpose, 512..527 attn vecs, rest deg count ----
__global__ void k_prep(const void* __restrict__ W1s, const void* __restrict__ al1,
                       const void* __restrict__ W1d, const void* __restrict__ ar1,
                       const void* __restrict__ W2s, const void* __restrict__ al2,
                       const void* __restrict__ W2d, const void* __restrict__ ar2,
                       const void* __restrict__ Wres2, const int* __restrict__ dst,
                       u16* __restrict__ BT1, u16* __restrict__ BT2,
                       float* __restrict__ wl1, float* __restrict__ wr1,
                       float* __restrict__ wl2, float* __restrict__ wr2,
                       int* __restrict__ deg, const int* __restrict__ mode) {
    int bid = blockIdx.x;
    if (bid >= 528) {
        int e = (bid - 528) * 256 + threadIdx.x;
        if (e < EE) atomicAdd(&deg[dst[e]], 1);
        return;
    }
    bool f32m = (*mode) != 0;
    if (bid < 512) {
        int id = bid * 256 + threadIdx.x;  // 0..131071
        int which = id >> 16;
        int rem = id & 65535;
        int n = rem >> 8, k = rem & 255;
        if (which == 0) {
            BT1[n * 256 + k] = f2bf(ld1(W1s, (size_t)k * 256 + n, f32m));
        } else {
            float v = (n < 128) ? ld1(W2s, (size_t)k * 128 + n, f32m)
                                : ld1(Wres2, (size_t)k * 128 + (n - 128), f32m);
            BT2[n * 256 + k] = f2bf(v);
        }
    } else {
        int id = (bid - 512) * 256 + threadIdx.x;  // 0..4095
        int which = id >> 10;
        int rem = id & 1023;
        int k = rem >> 2, h = rem & 3;
        float s = 0.f;
        if (which == 0) {
            for (int d = 0; d < 64; ++d) s += ld1(W1s, k * 256 + h * 64 + d, f32m) * ld1(al1, h * 64 + d, f32m);
            wl1[k * 4 + h] = s;
        } else if (which == 1) {
            for (int d = 0; d < 64; ++d) s += ld1(W1d, k * 256 + h * 64 + d, f32m) * ld1(ar1, h * 64 + d, f32m);
            wr1[k * 4 + h] = s;
        } else if (which == 2) {
            for (int d = 0; d < 32; ++d) s += ld1(W2s, k * 128 + h * 32 + d, f32m) * ld1(al2, h * 32 + d, f32m);
            wl2[k * 4 + h] = s;
        } else {
            for (int d = 0; d < 32; ++d) s += ld1(W2d, k * 128 + h * 32 + d, f32m) * ld1(ar2, h * 32 + d, f32m);
            wr2[k * 4 + h] = s;
        }
    }
}

// ---- multi-block CSR scan (parallel; single-block version was a 120us disaster) ----
__global__ void k_scan1(const int* __restrict__ deg, int* __restrict__ rowptr,
                        int* __restrict__ bsum) {
    __shared__ int sm[512];
    int t = threadIdx.x;
    int i = blockIdx.x * 512 + t;
    int v = (i < NN) ? deg[i] : 0;
    int x = v;
    sm[t] = x;
    __syncthreads();
    for (int off = 1; off < 512; off <<= 1) {
        int y = (t >= off) ? sm[t - off] : 0;
        __syncthreads();
        x += y;
        sm[t] = x;
        __syncthreads();
    }
    if (i < NN) rowptr[i] = x - v;
    if (t == 511) bsum[blockIdx.x] = x;
}

__global__ void k_scan2(const int* __restrict__ bsum, int* __restrict__ boff) {
    __shared__ int sm[128];
    int t = threadIdx.x;
    int v = (t < NBLK_SCAN) ? bsum[t] : 0;
    int x = v;
    sm[t] = x;
    __syncthreads();
    for (int off = 1; off < 128; off <<= 1) {
        int y = (t >= off) ? sm[t - off] : 0;
        __syncthreads();
        x += y;
        sm[t] = x;
        __syncthreads();
    }
    if (t < NBLK_SCAN) boff[t] = x - v;
}

__global__ void k_scan3(int* __restrict__ rowptr, const int* __restrict__ boff,
                        int* __restrict__ cursor) {
    int i = blockIdx.x * 256 + threadIdx.x;
    if (i < NN) {
        int r = rowptr[i] + boff[i >> 9];
        rowptr[i] = r;
        cursor[i] = r;
        if (i == 0) rowptr[NN] = EE;
    }
}

__global__ void k_scatter(const int* __restrict__ src, const int* __restrict__ dst,
                          int* __restrict__ cursor, int* __restrict__ csrc) {
    int e = blockIdx.x * 256 + threadIdx.x;
    if (e < EE) {
        int d = dst[e];
        int slot = atomicAdd(&cursor[d], 1);
        csrc[slot] = src[e];
    }
}

// ---- el/er: el[node][4] = sum_k X[node][k]*wl[k][h]  (float4 per node) ----
__global__ void k_eler(const void* __restrict__ X,
                       const float* __restrict__ wl, const float* __restrict__ wr,
                       float* __restrict__ el, float* __restrict__ er,
                       const int* __restrict__ mode) {
    bool f32m = (*mode) != 0;
    int wave = threadIdx.x >> 6, lane = threadIdx.x & 63;
    int node = blockIdx.x * 4 + wave;
    float a[4];
    load4(X, (size_t)node * 64 + lane, f32m, a);
    float accl[4] = {0, 0, 0, 0}, accr[4] = {0, 0, 0, 0};
    int k0 = lane * 4;
#pragma unroll
    for (int j = 0; j < 4; ++j) {
        float4 wlv = ((const float4*)wl)[k0 + j];
        float4 wrv = ((const float4*)wr)[k0 + j];
        accl[0] += a[j] * wlv.x; accl[1] += a[j] * wlv.y;
        accl[2] += a[j] * wlv.z; accl[3] += a[j] * wlv.w;
        accr[0] += a[j] * wrv.x; accr[1] += a[j] * wrv.y;
        accr[2] += a[j] * wrv.z; accr[3] += a[j] * wrv.w;
    }
#pragma unroll
    for (int off = 32; off > 0; off >>= 1) {
#pragma unroll
        for (int t = 0; t < 4; ++t) {
            accl[t] += __shfl_down(accl[t], off, 64);
            accr[t] += __shfl_down(accr[t], off, 64);
        }
    }
    if (lane == 0) {
        float4 vl = {accl[0], accl[1], accl[2], accl[3]};
        float4 vr = {accr[0], accr[1], accr[2], accr[3]};
        ((float4*)el)[node] = vl;
        ((float4*)er)[node] = vr;
    }
}

// ---- MFMA GEMM: C[M][256] bf16 = A[M][256] @ B (BT transposed [256n][256k]) ----
// 128x128 C-tile per block (4 waves, 2x2); BK=64, 4 phases. LDS pad 72 u16/row.
__global__ void k_gemm_mfma(const void* __restrict__ A, int aDual,
                            const u16* __restrict__ BT, u16* __restrict__ C,
                            const int* __restrict__ mode) {
    bool af32 = aDual && ((*mode) != 0);
    __shared__ u16 At[128 * 72];
    __shared__ u16 Bt[128 * 72];
    int t = threadIdx.x;
    int lane = t & 63, w = t >> 6;
    int mt = blockIdx.x >> 1, nt = blockIdx.x & 1;
    int m0 = mt * 128, n0 = nt * 128;
    int wr = (w >> 1) * 64, wc = (w & 1) * 64;
    f32x4 acc[4][4] = {};
    int q = lane >> 4, cl = lane & 15;

    for (int ph = 0; ph < 4; ++ph) {
        int kb = ph * 64;
        for (int it = 0; it < 4; ++it) {
            int c = it * 256 + t;
            int row = c >> 3, c8 = c & 7;
            int rowg = m0 + row;
            if (af32) {
                if (rowg < NN) {
                    const float* ap = (const float*)A + (size_t)rowg * 256 + kb + c8 * 8;
                    float4 v0 = ((const float4*)ap)[0];
                    float4 v1 = ((const float4*)ap)[1];
                    ushort4 lo = {f2bf(v0.x), f2bf(v0.y), f2bf(v0.z), f2bf(v0.w)};
                    ushort4 hi = {f2bf(v1.x), f2bf(v1.y), f2bf(v1.z), f2bf(v1.w)};
                    *(ushort4*)&At[row * 72 + c8 * 8] = lo;
                    *(ushort4*)&At[row * 72 + c8 * 8 + 4] = hi;
                } else {
                    ushort4 z = {0, 0, 0, 0};
                    *(ushort4*)&At[row * 72 + c8 * 8] = z;
                    *(ushort4*)&At[row * 72 + c8 * 8 + 4] = z;
                }
            } else {
                float4 av;
                if (rowg < NN) {
                    av = *(const float4*)((const u16*)A + (size_t)rowg * 256 + kb + c8 * 8);
                } else {
                    av = make_float4(0.f, 0.f, 0.f, 0.f);
                }
                *(float4*)&At[row * 72 + c8 * 8] = av;
            }
            float4 bv = *(const float4*)(BT + (size_t)(n0 + row) * 256 + kb + c8 * 8);
            *(float4*)&Bt[row * 72 + c8 * 8] = bv;
        }
        __syncthreads();
#pragma unroll
        for (int ks = 0; ks < 2; ++ks) {
            short8 af[4], bf[4];
#pragma unroll
            for (int i = 0; i < 4; ++i)
                af[i] = *(const short8*)&At[(wr + i * 16 + cl) * 72 + ks * 32 + q * 8];
#pragma unroll
            for (int j = 0; j < 4; ++j)
                bf[j] = *(const short8*)&Bt[(wc + j * 16 + cl) * 72 + ks * 32 + q * 8];
#pragma unroll
            for (int i = 0; i < 4; ++i)
#pragma unroll
                for (int j = 0; j < 4; ++j)
                    acc[i][j] = __builtin_amdgcn_mfma_f32_16x16x32_bf16(af[i], bf[j], acc[i][j], 0, 0, 0);
        }
        __syncthreads();
    }
#pragma unroll
    for (int i = 0; i < 4; ++i)
#pragma unroll
        for (int j = 0; j < 4; ++j)
#pragma unroll
            for (int r = 0; r < 4; ++r) {
                int mrow = m0 + wr + i * 16 + q * 4 + r;
                if (mrow < NN)
                    C[(size_t)mrow * 256 + n0 + wc + j * 16 + cl] = f2bf(acc[i][j][r]);
            }
}

// ---- layer-1 aggregation (single-pass no-max softmax) + fused eler2 ----
__global__ void k_agg1(const int* __restrict__ rowptr, const int* __restrict__ csrc,
                       const float* __restrict__ el, const float* __restrict__ er,
                       const u16* __restrict__ fs, const void* __restrict__ h_in,
                       u16* __restrict__ h1,
                       const float* __restrict__ wl2, const float* __restrict__ wr2,
                       float* __restrict__ el2, float* __restrict__ er2,
                       const int* __restrict__ mode) {
    bool f32m = (*mode) != 0;
    int wave = threadIdx.x >> 6, lane = threadIdx.x & 63;
    int node = blockIdx.x * 4 + wave;
    int beg = rowptr[node], end = rowptr[node + 1];
    int head = lane >> 4;
    float erh = er[node * 4 + head];
    float a0 = 0.f, a1 = 0.f, a2 = 0.f, a3 = 0.f, ll = 0.f;
#pragma unroll 2
    for (int p = beg; p < end; ++p) {
        int s = csrc[p];
        float e = el[s * 4 + head] + erh;
        e = e > 0.f ? e : 0.2f * e;
        e = fminf(fmaxf(e, -60.f), 60.f);
        float pw = __expf(e);
        ushort4 fv = *(const ushort4*)(fs + (size_t)s * 256 + lane * 4);
        ll += pw;
        a0 += pw * bf2f(fv.x);
        a1 += pw * bf2f(fv.y);
        a2 += pw * bf2f(fv.z);
        a3 += pw * bf2f(fv.w);
    }
    float rinv = 1.f / ll;
    float res[4];
    load4(h_in, (size_t)node * 64 + lane, f32m, res);
    float v0 = a0 * rinv + res[0], v1 = a1 * rinv + res[1];
    float v2 = a2 * rinv + res[2], v3 = a3 * rinv + res[3];
    v0 = v0 > 0.f ? v0 : __expf(v0) - 1.f;
    v1 = v1 > 0.f ? v1 : __expf(v1) - 1.f;
    v2 = v2 > 0.f ? v2 : __expf(v2) - 1.f;
    v3 = v3 > 0.f ? v3 : __expf(v3) - 1.f;
    ushort4 o = {f2bf(v0), f2bf(v1), f2bf(v2), f2bf(v3)};
    ((ushort4*)h1)[(size_t)node * 64 + lane] = o;
    // fused eler2: lane owns h1 cols lane*4..+3
    float4 w0 = ((const float4*)wl2)[lane * 4 + 0];
    float4 w1 = ((const float4*)wl2)[lane * 4 + 1];
    float4 w2 = ((const float4*)wl2)[lane * 4 + 2];
    float4 w3 = ((const float4*)wl2)[lane * 4 + 3];
    float4 r0 = ((const float4*)wr2)[lane * 4 + 0];
    float4 r1 = ((const float4*)wr2)[lane * 4 + 1];
    float4 r2 = ((const float4*)wr2)[lane * 4 + 2];
    float4 r3 = ((const float4*)wr2)[lane * 4 + 3];
    float acl[4], acr[4];
    acl[0] = v0 * w0.x + v1 * w1.x + v2 * w2.x + v3 * w3.x;
    acl[1] = v0 * w0.y + v1 * w1.y + v2 * w2.y + v3 * w3.y;
    acl[2] = v0 * w0.z + v1 * w1.z + v2 * w2.z + v3 * w3.z;
    acl[3] = v0 * w0.w + v1 * w1.w + v2 * w2.w + v3 * w3.w;
    acr[0] = v0 * r0.x + v1 * r1.x + v2 * r2.x + v3 * r3.x;
    acr[1] = v0 * r0.y + v1 * r1.y + v2 * r2.y + v3 * r3.y;
    acr[2] = v0 * r0.z + v1 * r1.z + v2 * r2.z + v3 * r3.z;
    acr[3] = v0 * r0.w + v1 * r1.w + v2 * r2.w + v3 * r3.w;
#pragma unroll
    for (int off = 32; off > 0; off >>= 1) {
#pragma unroll
        for (int t = 0; t < 4; ++t) {
            acl[t] += __shfl_down(acl[t], off, 64);
            acr[t] += __shfl_down(acr[t], off, 64);
        }
    }
    if (lane == 0) {
        float4 vl = {acl[0], acl[1], acl[2], acl[3]};
        float4 vr = {acr[0], acr[1], acr[2], acr[3]};
        ((float4*)el2)[node] = vl;
        ((float4*)er2)[node] = vr;
    }
}

// ---- layer-2 aggregation + residual + head-mean ----
// c2 layout: [node][256]: cols 0..127 = fs2 (h*32+d), cols 128..255 = res2
__global__ void k_agg2(const int* __restrict__ rowptr, const int* __restrict__ csrc,
                       const float* __restrict__ el, const float* __restrict__ er,
                       const u16* __restrict__ c2, void* __restrict__ out,
                       const int* __restrict__ mode) {
    bool f32m = (*mode) != 0;
    int wave = threadIdx.x >> 6, lane = threadIdx.x & 63;
    int node = blockIdx.x * 4 + wave;
    int beg = rowptr[node], end = rowptr[node + 1];
    int head = lane >> 4;
    float erh = er[node * 4 + head];
    float a0 = 0.f, a1 = 0.f, ll = 0.f;
#pragma unroll 2
    for (int p = beg; p < end; ++p) {
        int s = csrc[p];
        float e = el[s * 4 + head] + erh;
        e = e > 0.f ? e : 0.2f * e;
        e = fminf(fmaxf(e, -60.f), 60.f);
        float pw = __expf(e);
        ushort2 fv = *(const ushort2*)(c2 + (size_t)s * 256 + lane * 2);
        ll += pw;
        a0 += pw * bf2f(fv.x);
        a1 += pw * bf2f(fv.y);
    }
    float rinv = 1.f / ll;
    ushort2 rv = *(const ushort2*)(c2 + (size_t)node * 256 + 128 + lane * 2);
    float o0 = a0 * rinv + bf2f(rv.x);
    float o1 = a1 * rinv + bf2f(rv.y);
    o0 += __shfl_xor(o0, 16, 64); o0 += __shfl_xor(o0, 32, 64);
    o1 += __shfl_xor(o1, 16, 64); o1 += __shfl_xor(o1, 32, 64);
    if (lane < 16) {
        float v0 = 0.25f * o0, v1 = 0.25f * o1;
        size_t oi = (size_t)node * 32 + lane * 2;
        if (f32m) {
            ((float*)out)[oi] = v0;
            ((float*)out)[oi + 1] = v1;
        } else {
            ushort2 ov = {f2bf(v0), f2bf(v1)};
            *(ushort2*)((u16*)out + oi) = ov;
        }
    }
}

extern "C" void kernel_launch(void* const* d_in, const int* in_sizes, int n_in,
                              void* d_out, int out_size, void* d_ws, size_t ws_size,
                              hipStream_t stream) {
    int ih = 0, isrc = 1, idst = 2, iW1s = 3, iW1d = 4, ial1 = 5, iar1 = 6,
        iW2s = 7, iW2d = 8, ial2 = 9, iar2 = 10, iWres = 11;
    if (n_in >= 12 && in_sizes[0] != 12800000) {
        iW1d = 0; iW1s = 1; iW2d = 2; iW2s = 3; iWres = 4; ial1 = 5; ial2 = 6;
        iar1 = 7; iar2 = 8; idst = 9; ih = 10; isrc = 11;
    }
    const void* h     = d_in[ih];
    const int* src    = (const int*)d_in[isrc];
    const int* dst    = (const int*)d_in[idst];
    const void* W1s   = d_in[iW1s];
    const void* W1d   = d_in[iW1d];
    const void* al1   = d_in[ial1];
    const void* ar1   = d_in[iar1];
    const void* W2s   = d_in[iW2s];
    const void* W2d   = d_in[iW2d];
    const void* al2   = d_in[ial2];
    const void* ar2   = d_in[iar2];
    const void* Wres2 = d_in[iWres];

    char* w = (char*)d_ws;
    size_t off = 0;
    auto alloc = [&](size_t bytes) -> void* {
        void* p = w + off;
        off += (bytes + 255) & ~(size_t)255;
        return p;
    };
    int* mode   = (int*)alloc(256);
    float* wl1 = (float*)alloc(256 * 4 * 4);
    float* wr1 = (float*)alloc(256 * 4 * 4);
    float* wl2 = (float*)alloc(256 * 4 * 4);
    float* wr2 = (float*)alloc(256 * 4 * 4);
    int* deg    = (int*)alloc(NN * 4);
    int* cursor = (int*)alloc(NN * 4);
    int* rowptr = (int*)alloc((NN + 1) * 4);
    int* bsum   = (int*)alloc(NBLK_SCAN * 4);
    int* boff   = (int*)alloc(NBLK_SCAN * 4);
    int* csrc   = (int*)alloc((size_t)EE * 4);
    float* el1  = (float*)alloc((size_t)NN * 4 * 4);
    float* er1  = (float*)alloc((size_t)NN * 4 * 4);
    float* el2  = (float*)alloc((size_t)NN * 4 * 4);
    float* er2  = (float*)alloc((size_t)NN * 4 * 4);
    u16* BT1    = (u16*)alloc(256 * 256 * 2);
    u16* BT2    = (u16*)alloc(256 * 256 * 2);
    u16* fs1    = (u16*)alloc((size_t)NN * 256 * 2);   // 25.6 MB
    u16* h1     = (u16*)alloc((size_t)NN * 256 * 2);   // 25.6 MB
    u16* c2     = fs1;   // fs1 dead after k_agg1; c2 = [fs2 | res2]

    // 1: detect + zero deg
    k_detect<<<197, 256, 0, stream>>>((const u16*)h, mode, deg);
    // 2: B-transpose + attn vecs + deg count
    k_prep<<<528 + (EE + 255) / 256, 256, 0, stream>>>(
        W1s, al1, W1d, ar1, W2s, al2, W2d, ar2, Wres2, dst,
        BT1, BT2, wl1, wr1, wl2, wr2, deg, mode);
    // 3-5: multi-block CSR scan
    k_scan1<<<NBLK_SCAN, 512, 0, stream>>>(deg, rowptr, bsum);
    k_scan2<<<1, 128, 0, stream>>>(bsum, boff);
    k_scan3<<<(NN + 255) / 256, 256, 0, stream>>>(rowptr, boff, cursor);
    // 6: edge scatter
    k_scatter<<<(EE + 255) / 256, 256, 0, stream>>>(src, dst, cursor, csrc);
    // 7: eler1
    k_eler<<<NN / 4, 256, 0, stream>>>(h, wl1, wr1, el1, er1, mode);
    // 8: layer-1 GEMM
    k_gemm_mfma<<<782, 256, 0, stream>>>(h, 1, BT1, fs1, mode);
    // 9: layer-1 aggregation + fused eler2
    k_agg1<<<NN / 4, 256, 0, stream>>>(rowptr, csrc, el1, er1, fs1, h, h1,
                                       wl2, wr2, el2, er2, mode);
    // 10: layer-2 fused GEMM [W2s | Wres2]
    k_gemm_mfma<<<782, 256, 0, stream>>>(h1, 0, BT2, c2, mode);
    // 11: layer-2 aggregation + residual + head-mean
    k_agg2<<<NN / 4, 256, 0, stream>>>(rowptr, csrc, el2, er2, c2, d_out, mode);
}

// Round 11
// 403.060 us; speedup vs baseline: 1.3622x; 1.0293x over previous
//
#include <hip/hip_runtime.h>
#include <hip/hip_bf16.h>

#define NN 50000
#define EE 850000
#define NBLK_SCAN 98  // ceil(50000/512)

typedef unsigned short u16;
using short8 = __attribute__((ext_vector_type(8))) short;
using f32x4  = __attribute__((ext_vector_type(4))) float;

__device__ __forceinline__ float bf2f(u16 u) {
    union { unsigned int i; float f; } v; v.i = ((unsigned int)u) << 16; return v.f;
}
__device__ __forceinline__ u16 f2bf(float f) {
    __hip_bfloat16 h = __float2bfloat16(f);
    return *reinterpret_cast<u16*>(&h);
}

__device__ __forceinline__ float ld1(const void* X, size_t i, bool f32m) {
    return f32m ? ((const float*)X)[i] : bf2f(((const u16*)X)[i]);
}
__device__ __forceinline__ void load4(const void* X, size_t g, bool f32m, float o[4]) {
    if (f32m) {
        float4 v = ((const float4*)X)[g];
        o[0] = v.x; o[1] = v.y; o[2] = v.z; o[3] = v.w;
    } else {
        ushort4 v = ((const ushort4*)X)[g];
        o[0] = bf2f(v.x); o[1] = bf2f(v.y); o[2] = bf2f(v.z); o[3] = bf2f(v.w);
    }
}

// ---- block 0: dtype detect; blocks 1..196: zero deg ----
__global__ void k_detect(const u16* __restrict__ hh, int* __restrict__ flag,
                         int* __restrict__ deg) {
    if (blockIdx.x != 0) {
        int i = (blockIdx.x - 1) * 256 + threadIdx.x;
        if (i < NN) deg[i] = 0;
        return;
    }
    __shared__ int sm[256];
    int t = threadIdx.x;
    int c = 0;
    for (int i = 0; i < 16; ++i) {
        u16 u = hh[t * 16 + i];
        int e = (u >> 7) & 0xFF;
        if (e != 0 && (e < 90 || e > 160)) ++c;
    }
    sm[t] = c;
    __syncthreads();
    for (int s = 128; s > 0; s >>= 1) {
        if (t < s) sm[t] += sm[t + s];
        __syncthreads();
    }
    if (t == 0) *flag = (sm[0] > 200) ? 1 : 0;
}

// ---- fused prep: 0..511 B-transpose, 512..527 attn vecs, rest deg count ----
__global__ void k_prep(const void* __restrict__ W1s, const void* __restrict__ al1,
                       const void* __restrict__ W1d, const void* __restrict__ ar1,
                       const void* __restrict__ W2s, const void* __restrict__ al2,
                       const void* __restrict__ W2d, const void* __restrict__ ar2,
                       const void* __restrict__ Wres2, const int* __restrict__ dst,
                       u16* __restrict__ BT1, u16* __restrict__ BT2,
                       float* __restrict__ wl1, float* __restrict__ wr1,
                       float* __restrict__ wl2, float* __restrict__ wr2,
                       int* __restrict__ deg, const int* __restrict__ mode) {
    int bid = blockIdx.x;
    if (bid >= 528) {
        int e = (bid - 528) * 256 + threadIdx.x;
        if (e < EE) atomicAdd(&deg[dst[e]], 1);
        return;
    }
    bool f32m = (*mode) != 0;
    if (bid < 512) {
        int id = bid * 256 + threadIdx.x;  // 0..131071
        int which = id >> 16;
        int rem = id & 65535;
        int n = rem >> 8, k = rem & 255;
        if (which == 0) {
            BT1[n * 256 + k] = f2bf(ld1(W1s, (size_t)k * 256 + n, f32m));
        } else {
            float v = (n < 128) ? ld1(W2s, (size_t)k * 128 + n, f32m)
                                : ld1(Wres2, (size_t)k * 128 + (n - 128), f32m);
            BT2[n * 256 + k] = f2bf(v);
        }
    } else {
        int id = (bid - 512) * 256 + threadIdx.x;  // 0..4095
        int which = id >> 10;
        int rem = id & 1023;
        int k = rem >> 2, h = rem & 3;
        float s = 0.f;
        if (which == 0) {
            for (int d = 0; d < 64; ++d) s += ld1(W1s, k * 256 + h * 64 + d, f32m) * ld1(al1, h * 64 + d, f32m);
            wl1[k * 4 + h] = s;
        } else if (which == 1) {
            for (int d = 0; d < 64; ++d) s += ld1(W1d, k * 256 + h * 64 + d, f32m) * ld1(ar1, h * 64 + d, f32m);
            wr1[k * 4 + h] = s;
        } else if (which == 2) {
            for (int d = 0; d < 32; ++d) s += ld1(W2s, k * 128 + h * 32 + d, f32m) * ld1(al2, h * 32 + d, f32m);
            wl2[k * 4 + h] = s;
        } else {
            for (int d = 0; d < 32; ++d) s += ld1(W2d, k * 128 + h * 32 + d, f32m) * ld1(ar2, h * 32 + d, f32m);
            wr2[k * 4 + h] = s;
        }
    }
}

// ---- multi-block CSR scan ----
__global__ void k_scan1(const int* __restrict__ deg, int* __restrict__ rowptr,
                        int* __restrict__ bsum) {
    __shared__ int sm[512];
    int t = threadIdx.x;
    int i = blockIdx.x * 512 + t;
    int v = (i < NN) ? deg[i] : 0;
    int x = v;
    sm[t] = x;
    __syncthreads();
    for (int off = 1; off < 512; off <<= 1) {
        int y = (t >= off) ? sm[t - off] : 0;
        __syncthreads();
        x += y;
        sm[t] = x;
        __syncthreads();
    }
    if (i < NN) rowptr[i] = x - v;
    if (t == 511) bsum[blockIdx.x] = x;
}

__global__ void k_scan2(const int* __restrict__ bsum, int* __restrict__ boff) {
    __shared__ int sm[128];
    int t = threadIdx.x;
    int v = (t < NBLK_SCAN) ? bsum[t] : 0;
    int x = v;
    sm[t] = x;
    __syncthreads();
    for (int off = 1; off < 128; off <<= 1) {
        int y = (t >= off) ? sm[t - off] : 0;
        __syncthreads();
        x += y;
        sm[t] = x;
        __syncthreads();
    }
    if (t < NBLK_SCAN) boff[t] = x - v;
}

// ---- fused: blocks 0..195 scan3; blocks 196.. eler1 (same thin resource class) ----
__global__ void k_scan3_eler1(int* __restrict__ rowptr, const int* __restrict__ boff,
                              int* __restrict__ cursor, const void* __restrict__ X,
                              const float* __restrict__ wl, const float* __restrict__ wr,
                              float* __restrict__ el, float* __restrict__ er,
                              const int* __restrict__ mode) {
    int bid = blockIdx.x;
    if (bid < 196) {
        int i = bid * 256 + threadIdx.x;
        if (i < NN) {
            int r = rowptr[i] + boff[i >> 9];
            rowptr[i] = r;
            cursor[i] = r;
            if (i == 0) rowptr[NN] = EE;
        }
        return;
    }
    bool f32m = (*mode) != 0;
    int wave = threadIdx.x >> 6, lane = threadIdx.x & 63;
    int node = (bid - 196) * 4 + wave;
    float a[4];
    load4(X, (size_t)node * 64 + lane, f32m, a);
    float accl[4] = {0, 0, 0, 0}, accr[4] = {0, 0, 0, 0};
    int k0 = lane * 4;
#pragma unroll
    for (int j = 0; j < 4; ++j) {
        float4 wlv = ((const float4*)wl)[k0 + j];
        float4 wrv = ((const float4*)wr)[k0 + j];
        accl[0] += a[j] * wlv.x; accl[1] += a[j] * wlv.y;
        accl[2] += a[j] * wlv.z; accl[3] += a[j] * wlv.w;
        accr[0] += a[j] * wrv.x; accr[1] += a[j] * wrv.y;
        accr[2] += a[j] * wrv.z; accr[3] += a[j] * wrv.w;
    }
#pragma unroll
    for (int off = 32; off > 0; off >>= 1) {
#pragma unroll
        for (int t = 0; t < 4; ++t) {
            accl[t] += __shfl_down(accl[t], off, 64);
            accr[t] += __shfl_down(accr[t], off, 64);
        }
    }
    if (lane == 0) {
        float4 vl = {accl[0], accl[1], accl[2], accl[3]};
        float4 vr = {accr[0], accr[1], accr[2], accr[3]};
        ((float4*)el)[node] = vl;
        ((float4*)er)[node] = vr;
    }
}

// ---- scatter + edge-parallel attention weights (layer 1) ----
// aw[slot][h] = exp(clamp(leaky(el[s][h]+er[d][h]))) bf16; normalized later in agg1.
__global__ void k_scatter(const int* __restrict__ src, const int* __restrict__ dst,
                          int* __restrict__ cursor, int* __restrict__ csrc,
                          const float* __restrict__ el, const float* __restrict__ er,
                          u16* __restrict__ aw) {
    int e = blockIdx.x * 256 + threadIdx.x;
    if (e >= EE) return;
    int s = src[e], d = dst[e];
    int slot = atomicAdd(&cursor[d], 1);
    csrc[slot] = s;
    float4 eL = ((const float4*)el)[s];
    float4 eR = ((const float4*)er)[d];
    float ev[4] = {eL.x + eR.x, eL.y + eR.y, eL.z + eR.z, eL.w + eR.w};
    ushort4 o;
    u16* op = (u16*)&o;
#pragma unroll
    for (int t = 0; t < 4; ++t) {
        float x = ev[t];
        x = x > 0.f ? x : 0.2f * x;
        x = fminf(fmaxf(x, -60.f), 60.f);
        op[t] = f2bf(__expf(x));
    }
    ((ushort4*)aw)[slot] = o;
}

// ---- MFMA GEMM: C[M][256] bf16 = A[M][256] @ B (BT transposed [256n][256k]) ----
__global__ void k_gemm_mfma(const void* __restrict__ A, int aDual,
                            const u16* __restrict__ BT, u16* __restrict__ C,
                            const int* __restrict__ mode) {
    bool af32 = aDual && ((*mode) != 0);
    __shared__ u16 At[128 * 72];
    __shared__ u16 Bt[128 * 72];
    int t = threadIdx.x;
    int lane = t & 63, w = t >> 6;
    int mt = blockIdx.x >> 1, nt = blockIdx.x & 1;
    int m0 = mt * 128, n0 = nt * 128;
    int wr = (w >> 1) * 64, wc = (w & 1) * 64;
    f32x4 acc[4][4] = {};
    int q = lane >> 4, cl = lane & 15;

    for (int ph = 0; ph < 4; ++ph) {
        int kb = ph * 64;
        for (int it = 0; it < 4; ++it) {
            int c = it * 256 + t;
            int row = c >> 3, c8 = c & 7;
            int rowg = m0 + row;
            if (af32) {
                if (rowg < NN) {
                    const float* ap = (const float*)A + (size_t)rowg * 256 + kb + c8 * 8;
                    float4 v0 = ((const float4*)ap)[0];
                    float4 v1 = ((const float4*)ap)[1];
                    ushort4 lo = {f2bf(v0.x), f2bf(v0.y), f2bf(v0.z), f2bf(v0.w)};
                    ushort4 hi = {f2bf(v1.x), f2bf(v1.y), f2bf(v1.z), f2bf(v1.w)};
                    *(ushort4*)&At[row * 72 + c8 * 8] = lo;
                    *(ushort4*)&At[row * 72 + c8 * 8 + 4] = hi;
                } else {
                    ushort4 z = {0, 0, 0, 0};
                    *(ushort4*)&At[row * 72 + c8 * 8] = z;
                    *(ushort4*)&At[row * 72 + c8 * 8 + 4] = z;
                }
            } else {
                float4 av;
                if (rowg < NN) {
                    av = *(const float4*)((const u16*)A + (size_t)rowg * 256 + kb + c8 * 8);
                } else {
                    av = make_float4(0.f, 0.f, 0.f, 0.f);
                }
                *(float4*)&At[row * 72 + c8 * 8] = av;
            }
            float4 bv = *(const float4*)(BT + (size_t)(n0 + row) * 256 + kb + c8 * 8);
            *(float4*)&Bt[row * 72 + c8 * 8] = bv;
        }
        __syncthreads();
#pragma unroll
        for (int ks = 0; ks < 2; ++ks) {
            short8 af[4], bf[4];
#pragma unroll
            for (int i = 0; i < 4; ++i)
                af[i] = *(const short8*)&At[(wr + i * 16 + cl) * 72 + ks * 32 + q * 8];
#pragma unroll
            for (int j = 0; j < 4; ++j)
                bf[j] = *(const short8*)&Bt[(wc + j * 16 + cl) * 72 + ks * 32 + q * 8];
#pragma unroll
            for (int i = 0; i < 4; ++i)
#pragma unroll
                for (int j = 0; j < 4; ++j)
                    acc[i][j] = __builtin_amdgcn_mfma_f32_16x16x32_bf16(af[i], bf[j], acc[i][j], 0, 0, 0);
        }
        __syncthreads();
    }
#pragma unroll
    for (int i = 0; i < 4; ++i)
#pragma unroll
        for (int j = 0; j < 4; ++j)
#pragma unroll
            for (int r = 0; r < 4; ++r) {
                int mrow = m0 + wr + i * 16 + q * 4 + r;
                if (mrow < NN)
                    C[(size_t)mrow * 256 + n0 + wc + j * 16 + cl] = f2bf(acc[i][j][r]);
            }
}

// ---- layer-1 aggregation: pure weighted gather (aw precomputed) + fused eler2 ----
__global__ void k_agg1(const int* __restrict__ rowptr, const int* __restrict__ csrc,
                       const u16* __restrict__ aw, const u16* __restrict__ fs,
                       const void* __restrict__ h_in, u16* __restrict__ h1,
                       const float* __restrict__ wl2, const float* __restrict__ wr2,
                       float* __restrict__ el2, float* __restrict__ er2,
                       const int* __restrict__ mode) {
    bool f32m = (*mode) != 0;
    int wave = threadIdx.x >> 6, lane = threadIdx.x & 63;
    int node = blockIdx.x * 4 + wave;
    int beg = rowptr[node], end = rowptr[node + 1];
    int head = lane >> 4;
    float a0 = 0.f, a1 = 0.f, a2 = 0.f, a3 = 0.f, ll = 0.f;
#pragma unroll 4
    for (int p = beg; p < end; ++p) {
        int s = csrc[p];
        float pw = bf2f(aw[(size_t)p * 4 + head]);
        ushort4 fv = *(const ushort4*)(fs + (size_t)s * 256 + lane * 4);
        ll += pw;
        a0 += pw * bf2f(fv.x);
        a1 += pw * bf2f(fv.y);
        a2 += pw * bf2f(fv.z);
        a3 += pw * bf2f(fv.w);
    }
    float rinv = 1.f / ll;
    float res[4];
    load4(h_in, (size_t)node * 64 + lane, f32m, res);
    float v0 = a0 * rinv + res[0], v1 = a1 * rinv + res[1];
    float v2 = a2 * rinv + res[2], v3 = a3 * rinv + res[3];
    v0 = v0 > 0.f ? v0 : __expf(v0) - 1.f;
    v1 = v1 > 0.f ? v1 : __expf(v1) - 1.f;
    v2 = v2 > 0.f ? v2 : __expf(v2) - 1.f;
    v3 = v3 > 0.f ? v3 : __expf(v3) - 1.f;
    ushort4 o = {f2bf(v0), f2bf(v1), f2bf(v2), f2bf(v3)};
    ((ushort4*)h1)[(size_t)node * 64 + lane] = o;
    // fused eler2: lane owns h1 cols lane*4..+3
    float4 w0 = ((const float4*)wl2)[lane * 4 + 0];
    float4 w1 = ((const float4*)wl2)[lane * 4 + 1];
    float4 w2 = ((const float4*)wl2)[lane * 4 + 2];
    float4 w3 = ((const float4*)wl2)[lane * 4 + 3];
    float4 r0 = ((const float4*)wr2)[lane * 4 + 0];
    float4 r1 = ((const float4*)wr2)[lane * 4 + 1];
    float4 r2 = ((const float4*)wr2)[lane * 4 + 2];
    float4 r3 = ((const float4*)wr2)[lane * 4 + 3];
    float acl[4], acr[4];
    acl[0] = v0 * w0.x + v1 * w1.x + v2 * w2.x + v3 * w3.x;
    acl[1] = v0 * w0.y + v1 * w1.y + v2 * w2.y + v3 * w3.y;
    acl[2] = v0 * w0.z + v1 * w1.z + v2 * w2.z + v3 * w3.z;
    acl[3] = v0 * w0.w + v1 * w1.w + v2 * w2.w + v3 * w3.w;
    acr[0] = v0 * r0.x + v1 * r1.x + v2 * r2.x + v3 * r3.x;
    acr[1] = v0 * r0.y + v1 * r1.y + v2 * r2.y + v3 * r3.y;
    acr[2] = v0 * r0.z + v1 * r1.z + v2 * r2.z + v3 * r3.z;
    acr[3] = v0 * r0.w + v1 * r1.w + v2 * r2.w + v3 * r3.w;
#pragma unroll
    for (int off = 32; off > 0; off >>= 1) {
#pragma unroll
        for (int t = 0; t < 4; ++t) {
            acl[t] += __shfl_down(acl[t], off, 64);
            acr[t] += __shfl_down(acr[t], off, 64);
        }
    }
    if (lane == 0) {
        float4 vl = {acl[0], acl[1], acl[2], acl[3]};
        float4 vr = {acr[0], acr[1], acr[2], acr[3]};
        ((float4*)el2)[node] = vl;
        ((float4*)er2)[node] = vr;
    }
}

// ---- layer-2 aggregation + residual + head-mean (inline scores) ----
__global__ void k_agg2(const int* __restrict__ rowptr, const int* __restrict__ csrc,
                       const float* __restrict__ el, const float* __restrict__ er,
                       const u16* __restrict__ c2, void* __restrict__ out,
                       const int* __restrict__ mode) {
    bool f32m = (*mode) != 0;
    int wave = threadIdx.x >> 6, lane = threadIdx.x & 63;
    int node = blockIdx.x * 4 + wave;
    int beg = rowptr[node], end = rowptr[node + 1];
    int head = lane >> 4;
    float erh = er[node * 4 + head];
    float a0 = 0.f, a1 = 0.f, ll = 0.f;
#pragma unroll 2
    for (int p = beg; p < end; ++p) {
        int s = csrc[p];
        float e = el[s * 4 + head] + erh;
        e = e > 0.f ? e : 0.2f * e;
        e = fminf(fmaxf(e, -60.f), 60.f);
        float pw = __expf(e);
        ushort2 fv = *(const ushort2*)(c2 + (size_t)s * 256 + lane * 2);
        ll += pw;
        a0 += pw * bf2f(fv.x);
        a1 += pw * bf2f(fv.y);
    }
    float rinv = 1.f / ll;
    ushort2 rv = *(const ushort2*)(c2 + (size_t)node * 256 + 128 + lane * 2);
    float o0 = a0 * rinv + bf2f(rv.x);
    float o1 = a1 * rinv + bf2f(rv.y);
    o0 += __shfl_xor(o0, 16, 64); o0 += __shfl_xor(o0, 32, 64);
    o1 += __shfl_xor(o1, 16, 64); o1 += __shfl_xor(o1, 32, 64);
    if (lane < 16) {
        float v0 = 0.25f * o0, v1 = 0.25f * o1;
        size_t oi = (size_t)node * 32 + lane * 2;
        if (f32m) {
            ((float*)out)[oi] = v0;
            ((float*)out)[oi + 1] = v1;
        } else {
            ushort2 ov = {f2bf(v0), f2bf(v1)};
            *(ushort2*)((u16*)out + oi) = ov;
        }
    }
}

extern "C" void kernel_launch(void* const* d_in, const int* in_sizes, int n_in,
                              void* d_out, int out_size, void* d_ws, size_t ws_size,
                              hipStream_t stream) {
    int ih = 0, isrc = 1, idst = 2, iW1s = 3, iW1d = 4, ial1 = 5, iar1 = 6,
        iW2s = 7, iW2d = 8, ial2 = 9, iar2 = 10, iWres = 11;
    if (n_in >= 12 && in_sizes[0] != 12800000) {
        iW1d = 0; iW1s = 1; iW2d = 2; iW2s = 3; iWres = 4; ial1 = 5; ial2 = 6;
        iar1 = 7; iar2 = 8; idst = 9; ih = 10; isrc = 11;
    }
    const void* h     = d_in[ih];
    const int* src    = (const int*)d_in[isrc];
    const int* dst    = (const int*)d_in[idst];
    const void* W1s   = d_in[iW1s];
    const void* W1d   = d_in[iW1d];
    const void* al1   = d_in[ial1];
    const void* ar1   = d_in[iar1];
    const void* W2s   = d_in[iW2s];
    const void* W2d   = d_in[iW2d];
    const void* al2   = d_in[ial2];
    const void* ar2   = d_in[iar2];
    const void* Wres2 = d_in[iWres];

    char* w = (char*)d_ws;
    size_t off = 0;
    auto alloc = [&](size_t bytes) -> void* {
        void* p = w + off;
        off += (bytes + 255) & ~(size_t)255;
        return p;
    };
    int* mode   = (int*)alloc(256);
    float* wl1 = (float*)alloc(256 * 4 * 4);
    float* wr1 = (float*)alloc(256 * 4 * 4);
    float* wl2 = (float*)alloc(256 * 4 * 4);
    float* wr2 = (float*)alloc(256 * 4 * 4);
    int* deg    = (int*)alloc(NN * 4);
    int* cursor = (int*)alloc(NN * 4);
    int* rowptr = (int*)alloc((NN + 1) * 4);
    int* bsum   = (int*)alloc(NBLK_SCAN * 4);
    int* boff   = (int*)alloc(NBLK_SCAN * 4);
    int* csrc   = (int*)alloc((size_t)EE * 4);
    u16* aw     = (u16*)alloc((size_t)EE * 4 * 2);     // 6.8 MB
    float* el1  = (float*)alloc((size_t)NN * 4 * 4);
    float* er1  = (float*)alloc((size_t)NN * 4 * 4);
    float* el2  = (float*)alloc((size_t)NN * 4 * 4);
    float* er2  = (float*)alloc((size_t)NN * 4 * 4);
    u16* BT1    = (u16*)alloc(256 * 256 * 2);
    u16* BT2    = (u16*)alloc(256 * 256 * 2);
    u16* fs1    = (u16*)alloc((size_t)NN * 256 * 2);   // 25.6 MB
    u16* h1     = (u16*)alloc((size_t)NN * 256 * 2);   // 25.6 MB
    u16* c2     = fs1;   // fs1 dead after k_agg1; c2 = [fs2 | res2]

    // 1: detect + zero deg
    k_detect<<<197, 256, 0, stream>>>((const u16*)h, mode, deg);
    // 2: B-transpose + attn vecs + deg count
    k_prep<<<528 + (EE + 255) / 256, 256, 0, stream>>>(
        W1s, al1, W1d, ar1, W2s, al2, W2d, ar2, Wres2, dst,
        BT1, BT2, wl1, wr1, wl2, wr2, deg, mode);
    // 3-4: CSR scan (blocks)
    k_scan1<<<NBLK_SCAN, 512, 0, stream>>>(deg, rowptr, bsum);
    k_scan2<<<1, 128, 0, stream>>>(bsum, boff);
    // 5: scan3 + eler1 fused (thin kernels, same resource class)
    k_scan3_eler1<<<196 + NN / 4, 256, 0, stream>>>(rowptr, boff, cursor,
                                                    h, wl1, wr1, el1, er1, mode);
    // 6: scatter + edge-parallel layer-1 attention weights
    k_scatter<<<(EE + 255) / 256, 256, 0, stream>>>(src, dst, cursor, csrc,
                                                    el1, er1, aw);
    // 7: layer-1 GEMM
    k_gemm_mfma<<<782, 256, 0, stream>>>(h, 1, BT1, fs1, mode);
    // 8: layer-1 aggregation (weighted gather) + fused eler2
    k_agg1<<<NN / 4, 256, 0, stream>>>(rowptr, csrc, aw, fs1, h, h1,
                                       wl2, wr2, el2, er2, mode);
    // 9: layer-2 fused GEMM [W2s | Wres2]
    k_gemm_mfma<<<782, 256, 0, stream>>>(h1, 0, BT2, c2, mode);
    // 10: layer-2 aggregation + residual + head-mean
    k_agg2<<<NN / 4, 256, 0, stream>>>(rowptr, csrc, el2, er2, c2, d_out, mode);
}

// Round 12
// 375.349 us; speedup vs baseline: 1.4628x; 1.0738x over previous
//
#include <hip/hip_runtime.h>
#include <hip/hip_bf16.h>

#define NN 50000
#define EE 850000
#define NBLK_SCAN 98  // ceil(50000/512)

typedef unsigned short u16;
using short8 = __attribute__((ext_vector_type(8))) short;
using f32x4  = __attribute__((ext_vector_type(4))) float;

__device__ __forceinline__ float bf2f(u16 u) {
    union { unsigned int i; float f; } v; v.i = ((unsigned int)u) << 16; return v.f;
}
__device__ __forceinline__ u16 f2bf(float f) {
    __hip_bfloat16 h = __float2bfloat16(f);
    return *reinterpret_cast<u16*>(&h);
}

__device__ __forceinline__ float ld1(const void* X, size_t i, bool f32m) {
    return f32m ? ((const float*)X)[i] : bf2f(((const u16*)X)[i]);
}
__device__ __forceinline__ void load4(const void* X, size_t g, bool f32m, float o[4]) {
    if (f32m) {
        float4 v = ((const float4*)X)[g];
        o[0] = v.x; o[1] = v.y; o[2] = v.z; o[3] = v.w;
    } else {
        ushort4 v = ((const ushort4*)X)[g];
        o[0] = bf2f(v.x); o[1] = bf2f(v.y); o[2] = bf2f(v.z); o[3] = bf2f(v.w);
    }
}

// ---- block 0: dtype detect; blocks 1..196: zero deg ----
__global__ void k_detect(const u16* __restrict__ hh, int* __restrict__ flag,
                         int* __restrict__ deg) {
    if (blockIdx.x != 0) {
        int i = (blockIdx.x - 1) * 256 + threadIdx.x;
        if (i < NN) deg[i] = 0;
        return;
    }
    __shared__ int sm[256];
    int t = threadIdx.x;
    int c = 0;
    for (int i = 0; i < 16; ++i) {
        u16 u = hh[t * 16 + i];
        int e = (u >> 7) & 0xFF;
        if (e != 0 && (e < 90 || e > 160)) ++c;
    }
    sm[t] = c;
    __syncthreads();
    for (int s = 128; s > 0; s >>= 1) {
        if (t < s) sm[t] += sm[t + s];
        __syncthreads();
    }
    if (t == 0) *flag = (sm[0] > 200) ? 1 : 0;
}

// ---- fused prep: 0..511 B-transpose, 512..527 attn vecs, rest deg+rank ----
// eorder[e] = rank of edge e within its dst (atomic return value) -> slot
// computable later as rowptr[dst]+eorder without any further atomics.
__global__ void k_prep(const void* __restrict__ W1s, const void* __restrict__ al1,
                       const void* __restrict__ W1d, const void* __restrict__ ar1,
                       const void* __restrict__ W2s, const void* __restrict__ al2,
                       const void* __restrict__ W2d, const void* __restrict__ ar2,
                       const void* __restrict__ Wres2, const int* __restrict__ dst,
                       u16* __restrict__ BT1, u16* __restrict__ BT2,
                       float* __restrict__ wl1, float* __restrict__ wr1,
                       float* __restrict__ wl2, float* __restrict__ wr2,
                       int* __restrict__ deg, int* __restrict__ eorder,
                       const int* __restrict__ mode) {
    int bid = blockIdx.x;
    if (bid >= 528) {
        int e = (bid - 528) * 256 + threadIdx.x;
        if (e < EE) {
            int r = atomicAdd(&deg[dst[e]], 1);
            eorder[e] = r;
        }
        return;
    }
    bool f32m = (*mode) != 0;
    if (bid < 512) {
        int id = bid * 256 + threadIdx.x;  // 0..131071
        int which = id >> 16;
        int rem = id & 65535;
        int n = rem >> 8, k = rem & 255;
        if (which == 0) {
            BT1[n * 256 + k] = f2bf(ld1(W1s, (size_t)k * 256 + n, f32m));
        } else {
            float v = (n < 128) ? ld1(W2s, (size_t)k * 128 + n, f32m)
                                : ld1(Wres2, (size_t)k * 128 + (n - 128), f32m);
            BT2[n * 256 + k] = f2bf(v);
        }
    } else {
        int id = (bid - 512) * 256 + threadIdx.x;  // 0..4095
        int which = id >> 10;
        int rem = id & 1023;
        int k = rem >> 2, h = rem & 3;
        float s = 0.f;
        if (which == 0) {
            for (int d = 0; d < 64; ++d) s += ld1(W1s, k * 256 + h * 64 + d, f32m) * ld1(al1, h * 64 + d, f32m);
            wl1[k * 4 + h] = s;
        } else if (which == 1) {
            for (int d = 0; d < 64; ++d) s += ld1(W1d, k * 256 + h * 64 + d, f32m) * ld1(ar1, h * 64 + d, f32m);
            wr1[k * 4 + h] = s;
        } else if (which == 2) {
            for (int d = 0; d < 32; ++d) s += ld1(W2s, k * 128 + h * 32 + d, f32m) * ld1(al2, h * 32 + d, f32m);
            wl2[k * 4 + h] = s;
        } else {
            for (int d = 0; d < 32; ++d) s += ld1(W2d, k * 128 + h * 32 + d, f32m) * ld1(ar2, h * 32 + d, f32m);
            wr2[k * 4 + h] = s;
        }
    }
}

// ---- CSR scan stage 1: per-block inclusive scan + block sums ----
__global__ void k_scan1(const int* __restrict__ deg, int* __restrict__ rowptr,
                        int* __restrict__ bsum) {
    __shared__ int sm[512];
    int t = threadIdx.x;
    int i = blockIdx.x * 512 + t;
    int v = (i < NN) ? deg[i] : 0;
    int x = v;
    sm[t] = x;
    __syncthreads();
    for (int off = 1; off < 512; off <<= 1) {
        int y = (t >= off) ? sm[t - off] : 0;
        __syncthreads();
        x += y;
        sm[t] = x;
        __syncthreads();
    }
    if (i < NN) rowptr[i] = x - v;
    if (t == 511) bsum[blockIdx.x] = x;
}

// ---- fused: blocks 0..195 scan-finalize (inline bsum prefix); rest eler1 ----
__global__ void k_scan3_eler1(int* __restrict__ rowptr, const int* __restrict__ bsum,
                              const void* __restrict__ X,
                              const float* __restrict__ wl, const float* __restrict__ wr,
                              float* __restrict__ el, float* __restrict__ er,
                              const int* __restrict__ mode) {
    int bid = blockIdx.x;
    if (bid < 196) {
        __shared__ int sm[NBLK_SCAN];
        int t = threadIdx.x;
        if (t < NBLK_SCAN) sm[t] = bsum[t];
        __syncthreads();
        int g = bid >> 1;  // each block's 256 indices lie in one 512-group
        int pre = 0;
        for (int j = 0; j < g; ++j) pre += sm[j];  // LDS broadcast, uniform
        int i = bid * 256 + t;
        if (i < NN) {
            rowptr[i] += pre;
            if (i == 0) rowptr[NN] = EE;
        }
        return;
    }
    bool f32m = (*mode) != 0;
    int wave = threadIdx.x >> 6, lane = threadIdx.x & 63;
    int node = (bid - 196) * 4 + wave;
    float a[4];
    load4(X, (size_t)node * 64 + lane, f32m, a);
    float accl[4] = {0, 0, 0, 0}, accr[4] = {0, 0, 0, 0};
    int k0 = lane * 4;
#pragma unroll
    for (int j = 0; j < 4; ++j) {
        float4 wlv = ((const float4*)wl)[k0 + j];
        float4 wrv = ((const float4*)wr)[k0 + j];
        accl[0] += a[j] * wlv.x; accl[1] += a[j] * wlv.y;
        accl[2] += a[j] * wlv.z; accl[3] += a[j] * wlv.w;
        accr[0] += a[j] * wrv.x; accr[1] += a[j] * wrv.y;
        accr[2] += a[j] * wrv.z; accr[3] += a[j] * wrv.w;
    }
#pragma unroll
    for (int off = 32; off > 0; off >>= 1) {
#pragma unroll
        for (int t = 0; t < 4; ++t) {
            accl[t] += __shfl_down(accl[t], off, 64);
            accr[t] += __shfl_down(accr[t], off, 64);
        }
    }
    if (lane == 0) {
        float4 vl = {accl[0], accl[1], accl[2], accl[3]};
        float4 vr = {accr[0], accr[1], accr[2], accr[3]};
        ((float4*)el)[node] = vl;
        ((float4*)er)[node] = vr;
    }
}

// ---- edge-parallel weight gen (atomic-free): slot = rowptr[d]+eorder[e] ----
// writeCsrc=1: also scatter csrc (layer-1 pass doubles as CSR scatter).
__global__ void k_awgen(const int* __restrict__ src, const int* __restrict__ dst,
                        const int* __restrict__ eorder, const int* __restrict__ rowptr,
                        const float* __restrict__ el, const float* __restrict__ er,
                        u16* __restrict__ aw, int* __restrict__ csrc, int writeCsrc) {
    int e = blockIdx.x * 256 + threadIdx.x;
    if (e >= EE) return;
    int s = src[e], d = dst[e];
    int slot = rowptr[d] + eorder[e];
    if (writeCsrc) csrc[slot] = s;
    float4 eL = ((const float4*)el)[s];
    float4 eR = ((const float4*)er)[d];
    float ev[4] = {eL.x + eR.x, eL.y + eR.y, eL.z + eR.z, eL.w + eR.w};
    ushort4 o;
    u16* op = (u16*)&o;
#pragma unroll
    for (int t = 0; t < 4; ++t) {
        float x = ev[t];
        x = x > 0.f ? x : 0.2f * x;
        x = fminf(fmaxf(x, -60.f), 60.f);
        op[t] = f2bf(__expf(x));
    }
    ((ushort4*)aw)[slot] = o;
}

// ---- MFMA GEMM: C[M][256] bf16 = A[M][256] @ B (BT transposed [256n][256k]) ----
__global__ void k_gemm_mfma(const void* __restrict__ A, int aDual,
                            const u16* __restrict__ BT, u16* __restrict__ C,
                            const int* __restrict__ mode) {
    bool af32 = aDual && ((*mode) != 0);
    __shared__ u16 At[128 * 72];
    __shared__ u16 Bt[128 * 72];
    int t = threadIdx.x;
    int lane = t & 63, w = t >> 6;
    int mt = blockIdx.x >> 1, nt = blockIdx.x & 1;
    int m0 = mt * 128, n0 = nt * 128;
    int wr = (w >> 1) * 64, wc = (w & 1) * 64;
    f32x4 acc[4][4] = {};
    int q = lane >> 4, cl = lane & 15;

    for (int ph = 0; ph < 4; ++ph) {
        int kb = ph * 64;
        for (int it = 0; it < 4; ++it) {
            int c = it * 256 + t;
            int row = c >> 3, c8 = c & 7;
            int rowg = m0 + row;
            if (af32) {
                if (rowg < NN) {
                    const float* ap = (const float*)A + (size_t)rowg * 256 + kb + c8 * 8;
                    float4 v0 = ((const float4*)ap)[0];
                    float4 v1 = ((const float4*)ap)[1];
                    ushort4 lo = {f2bf(v0.x), f2bf(v0.y), f2bf(v0.z), f2bf(v0.w)};
                    ushort4 hi = {f2bf(v1.x), f2bf(v1.y), f2bf(v1.z), f2bf(v1.w)};
                    *(ushort4*)&At[row * 72 + c8 * 8] = lo;
                    *(ushort4*)&At[row * 72 + c8 * 8 + 4] = hi;
                } else {
                    ushort4 z = {0, 0, 0, 0};
                    *(ushort4*)&At[row * 72 + c8 * 8] = z;
                    *(ushort4*)&At[row * 72 + c8 * 8 + 4] = z;
                }
            } else {
                float4 av;
                if (rowg < NN) {
                    av = *(const float4*)((const u16*)A + (size_t)rowg * 256 + kb + c8 * 8);
                } else {
                    av = make_float4(0.f, 0.f, 0.f, 0.f);
                }
                *(float4*)&At[row * 72 + c8 * 8] = av;
            }
            float4 bv = *(const float4*)(BT + (size_t)(n0 + row) * 256 + kb + c8 * 8);
            *(float4*)&Bt[row * 72 + c8 * 8] = bv;
        }
        __syncthreads();
#pragma unroll
        for (int ks = 0; ks < 2; ++ks) {
            short8 af[4], bf[4];
#pragma unroll
            for (int i = 0; i < 4; ++i)
                af[i] = *(const short8*)&At[(wr + i * 16 + cl) * 72 + ks * 32 + q * 8];
#pragma unroll
            for (int j = 0; j < 4; ++j)
                bf[j] = *(const short8*)&Bt[(wc + j * 16 + cl) * 72 + ks * 32 + q * 8];
#pragma unroll
            for (int i = 0; i < 4; ++i)
#pragma unroll
                for (int j = 0; j < 4; ++j)
                    acc[i][j] = __builtin_amdgcn_mfma_f32_16x16x32_bf16(af[i], bf[j], acc[i][j], 0, 0, 0);
        }
        __syncthreads();
    }
#pragma unroll
    for (int i = 0; i < 4; ++i)
#pragma unroll
        for (int j = 0; j < 4; ++j)
#pragma unroll
            for (int r = 0; r < 4; ++r) {
                int mrow = m0 + wr + i * 16 + q * 4 + r;
                if (mrow < NN)
                    C[(size_t)mrow * 256 + n0 + wc + j * 16 + cl] = f2bf(acc[i][j][r]);
            }
}

// ---- layer-1 aggregation: pure weighted gather (aw precomputed) + fused eler2 ----
__global__ void k_agg1(const int* __restrict__ rowptr, const int* __restrict__ csrc,
                       const u16* __restrict__ aw, const u16* __restrict__ fs,
                       const void* __restrict__ h_in, u16* __restrict__ h1,
                       const float* __restrict__ wl2, const float* __restrict__ wr2,
                       float* __restrict__ el2, float* __restrict__ er2,
                       const int* __restrict__ mode) {
    bool f32m = (*mode) != 0;
    int wave = threadIdx.x >> 6, lane = threadIdx.x & 63;
    int node = blockIdx.x * 4 + wave;
    int beg = rowptr[node], end = rowptr[node + 1];
    int head = lane >> 4;
    float a0 = 0.f, a1 = 0.f, a2 = 0.f, a3 = 0.f, ll = 0.f;
#pragma unroll 8
    for (int p = beg; p < end; ++p) {
        int s = csrc[p];
        float pw = bf2f(aw[(size_t)p * 4 + head]);
        ushort4 fv = *(const ushort4*)(fs + (size_t)s * 256 + lane * 4);
        ll += pw;
        a0 += pw * bf2f(fv.x);
        a1 += pw * bf2f(fv.y);
        a2 += pw * bf2f(fv.z);
        a3 += pw * bf2f(fv.w);
    }
    float rinv = 1.f / ll;
    float res[4];
    load4(h_in, (size_t)node * 64 + lane, f32m, res);
    float v0 = a0 * rinv + res[0], v1 = a1 * rinv + res[1];
    float v2 = a2 * rinv + res[2], v3 = a3 * rinv + res[3];
    v0 = v0 > 0.f ? v0 : __expf(v0) - 1.f;
    v1 = v1 > 0.f ? v1 : __expf(v1) - 1.f;
    v2 = v2 > 0.f ? v2 : __expf(v2) - 1.f;
    v3 = v3 > 0.f ? v3 : __expf(v3) - 1.f;
    ushort4 o = {f2bf(v0), f2bf(v1), f2bf(v2), f2bf(v3)};
    ((ushort4*)h1)[(size_t)node * 64 + lane] = o;
    // fused eler2: lane owns h1 cols lane*4..+3
    float4 w0 = ((const float4*)wl2)[lane * 4 + 0];
    float4 w1 = ((const float4*)wl2)[lane * 4 + 1];
    float4 w2 = ((const float4*)wl2)[lane * 4 + 2];
    float4 w3 = ((const float4*)wl2)[lane * 4 + 3];
    float4 r0 = ((const float4*)wr2)[lane * 4 + 0];
    float4 r1 = ((const float4*)wr2)[lane * 4 + 1];
    float4 r2 = ((const float4*)wr2)[lane * 4 + 2];
    float4 r3 = ((const float4*)wr2)[lane * 4 + 3];
    float acl[4], acr[4];
    acl[0] = v0 * w0.x + v1 * w1.x + v2 * w2.x + v3 * w3.x;
    acl[1] = v0 * w0.y + v1 * w1.y + v2 * w2.y + v3 * w3.y;
    acl[2] = v0 * w0.z + v1 * w1.z + v2 * w2.z + v3 * w3.z;
    acl[3] = v0 * w0.w + v1 * w1.w + v2 * w2.w + v3 * w3.w;
    acr[0] = v0 * r0.x + v1 * r1.x + v2 * r2.x + v3 * r3.x;
    acr[1] = v0 * r0.y + v1 * r1.y + v2 * r2.y + v3 * r3.y;
    acr[2] = v0 * r0.z + v1 * r1.z + v2 * r2.z + v3 * r3.z;
    acr[3] = v0 * r0.w + v1 * r1.w + v2 * r2.w + v3 * r3.w;
#pragma unroll
    for (int off = 32; off > 0; off >>= 1) {
#pragma unroll
        for (int t = 0; t < 4; ++t) {
            acl[t] += __shfl_down(acl[t], off, 64);
            acr[t] += __shfl_down(acr[t], off, 64);
        }
    }
    if (lane == 0) {
        float4 vl = {acl[0], acl[1], acl[2], acl[3]};
        float4 vr = {acr[0], acr[1], acr[2], acr[3]};
        ((float4*)el2)[node] = vl;
        ((float4*)er2)[node] = vr;
    }
}

// ---- layer-2 aggregation: pure weighted gather + residual + head-mean ----
__global__ void k_agg2(const int* __restrict__ rowptr, const int* __restrict__ csrc,
                       const u16* __restrict__ aw, const u16* __restrict__ c2,
                       void* __restrict__ out, const int* __restrict__ mode) {
    bool f32m = (*mode) != 0;
    int wave = threadIdx.x >> 6, lane = threadIdx.x & 63;
    int node = blockIdx.x * 4 + wave;
    int beg = rowptr[node], end = rowptr[node + 1];
    int head = lane >> 4;
    float a0 = 0.f, a1 = 0.f, ll = 0.f;
#pragma unroll 8
    for (int p = beg; p < end; ++p) {
        int s = csrc[p];
        float pw = bf2f(aw[(size_t)p * 4 + head]);
        ushort2 fv = *(const ushort2*)(c2 + (size_t)s * 256 + lane * 2);
        ll += pw;
        a0 += pw * bf2f(fv.x);
        a1 += pw * bf2f(fv.y);
    }
    float rinv = 1.f / ll;
    ushort2 rv = *(const ushort2*)(c2 + (size_t)node * 256 + 128 + lane * 2);
    float o0 = a0 * rinv + bf2f(rv.x);
    float o1 = a1 * rinv + bf2f(rv.y);
    o0 += __shfl_xor(o0, 16, 64); o0 += __shfl_xor(o0, 32, 64);
    o1 += __shfl_xor(o1, 16, 64); o1 += __shfl_xor(o1, 32, 64);
    if (lane < 16) {
        float v0 = 0.25f * o0, v1 = 0.25f * o1;
        size_t oi = (size_t)node * 32 + lane * 2;
        if (f32m) {
            ((float*)out)[oi] = v0;
            ((float*)out)[oi + 1] = v1;
        } else {
            ushort2 ov = {f2bf(v0), f2bf(v1)};
            *(ushort2*)((u16*)out + oi) = ov;
        }
    }
}

extern "C" void kernel_launch(void* const* d_in, const int* in_sizes, int n_in,
                              void* d_out, int out_size, void* d_ws, size_t ws_size,
                              hipStream_t stream) {
    int ih = 0, isrc = 1, idst = 2, iW1s = 3, iW1d = 4, ial1 = 5, iar1 = 6,
        iW2s = 7, iW2d = 8, ial2 = 9, iar2 = 10, iWres = 11;
    if (n_in >= 12 && in_sizes[0] != 12800000) {
        iW1d = 0; iW1s = 1; iW2d = 2; iW2s = 3; iWres = 4; ial1 = 5; ial2 = 6;
        iar1 = 7; iar2 = 8; idst = 9; ih = 10; isrc = 11;
    }
    const void* h     = d_in[ih];
    const int* src    = (const int*)d_in[isrc];
    const int* dst    = (const int*)d_in[idst];
    const void* W1s   = d_in[iW1s];
    const void* W1d   = d_in[iW1d];
    const void* al1   = d_in[ial1];
    const void* ar1   = d_in[iar1];
    const void* W2s   = d_in[iW2s];
    const void* W2d   = d_in[iW2d];
    const void* al2   = d_in[ial2];
    const void* ar2   = d_in[iar2];
    const void* Wres2 = d_in[iWres];

    char* w = (char*)d_ws;
    size_t off = 0;
    auto alloc = [&](size_t bytes) -> void* {
        void* p = w + off;
        off += (bytes + 255) & ~(size_t)255;
        return p;
    };
    int* mode   = (int*)alloc(256);
    float* wl1 = (float*)alloc(256 * 4 * 4);
    float* wr1 = (float*)alloc(256 * 4 * 4);
    float* wl2 = (float*)alloc(256 * 4 * 4);
    float* wr2 = (float*)alloc(256 * 4 * 4);
    int* deg    = (int*)alloc(NN * 4);
    int* rowptr = (int*)alloc((NN + 1) * 4);
    int* bsum   = (int*)alloc(NBLK_SCAN * 4);
    int* eorder = (int*)alloc((size_t)EE * 4);
    int* csrc   = (int*)alloc((size_t)EE * 4);
    u16* aw     = (u16*)alloc((size_t)EE * 4 * 2);     // 6.8 MB (reused for layer 2)
    float* el1  = (float*)alloc((size_t)NN * 4 * 4);
    float* er1  = (float*)alloc((size_t)NN * 4 * 4);
    float* el2  = (float*)alloc((size_t)NN * 4 * 4);
    float* er2  = (float*)alloc((size_t)NN * 4 * 4);
    u16* BT1    = (u16*)alloc(256 * 256 * 2);
    u16* BT2    = (u16*)alloc(256 * 256 * 2);
    u16* fs1    = (u16*)alloc((size_t)NN * 256 * 2);   // 25.6 MB
    u16* h1     = (u16*)alloc((size_t)NN * 256 * 2);   // 25.6 MB
    u16* c2     = fs1;   // fs1 dead after k_agg1; c2 = [fs2 | res2]

    // 1: detect + zero deg
    k_detect<<<197, 256, 0, stream>>>((const u16*)h, mode, deg);
    // 2: B-transpose + attn vecs + deg count + edge ranks
    k_prep<<<528 + (EE + 255) / 256, 256, 0, stream>>>(
        W1s, al1, W1d, ar1, W2s, al2, W2d, ar2, Wres2, dst,
        BT1, BT2, wl1, wr1, wl2, wr2, deg, eorder, mode);
    // 3: scan stage 1
    k_scan1<<<NBLK_SCAN, 512, 0, stream>>>(deg, rowptr, bsum);
    // 4: scan finalize (inline bsum prefix) + eler1
    k_scan3_eler1<<<196 + NN / 4, 256, 0, stream>>>(rowptr, bsum,
                                                    h, wl1, wr1, el1, er1, mode);
    // 5: layer-1 weights + CSR scatter (atomic-free)
    k_awgen<<<(EE + 255) / 256, 256, 0, stream>>>(src, dst, eorder, rowptr,
                                                  el1, er1, aw, csrc, 1);
    // 6: layer-1 GEMM
    k_gemm_mfma<<<782, 256, 0, stream>>>(h, 1, BT1, fs1, mode);
    // 7: layer-1 aggregation (weighted gather) + fused eler2
    k_agg1<<<NN / 4, 256, 0, stream>>>(rowptr, csrc, aw, fs1, h, h1,
                                       wl2, wr2, el2, er2, mode);
    // 8: layer-2 fused GEMM [W2s | Wres2]
    k_gemm_mfma<<<782, 256, 0, stream>>>(h1, 0, BT2, c2, mode);
    // 9: layer-2 weights (atomic-free, aw buffer reused)
    k_awgen<<<(EE + 255) / 256, 256, 0, stream>>>(src, dst, eorder, rowptr,
                                                  el2, er2, aw, csrc, 0);
    // 10: layer-2 aggregation + residual + head-mean
    k_agg2<<<NN / 4, 256, 0, stream>>>(rowptr, csrc, aw, c2, d_out, mode);
}